// Round 1
// baseline (1318.437 us; speedup 1.0000x reference)
//
#include <hip/hip_runtime.h>

static constexpr int N_   = 50000;
static constexpr int E_   = 800000;
static constexpr int G_   = 512;
static constexpr int IN_  = 544;
static constexpr float EPS_ = 1e-5f;

// ---------------- workspace byte offsets ----------------
static constexpr size_t OFF_BN1SUM = 0;          // 512 f
static constexpr size_t OFF_BN1SQ  = 2048;       // 512 f
static constexpr size_t OFF_BN2SUM = 4096;       // 48 f
static constexpr size_t OFF_BN2SQ  = 4288;       // 48 f
static constexpr size_t OFF_BN3SUM = 4480;       // 256 f
static constexpr size_t OFF_BN3SQ  = 5504;       // 256 f
static constexpr size_t OFF_COUNT  = 6528;       // N ints
static constexpr size_t OFF_CUR    = 206528;     // N ints
static constexpr size_t ZERO_BYTES = 406528;     // one memset covers all of the above
static constexpr size_t OFF_OFFS   = 406528;     // N ints
static constexpr size_t OFF_PART   = 606592;     // 64 ints
static constexpr size_t OFF_WC2    = 606848;     // 512*16 f
static constexpr size_t OFF_C2     = 639616;     // 16 f
static constexpr size_t OFF_WP2    = 639744;     // 48*64 f
static constexpr size_t OFF_CP     = 652032;     // 64 f
static constexpr size_t OFF_WGT    = 652288;     // 64*256 f
static constexpr size_t OFF_SC3    = 717824;     // 256 f
static constexpr size_t OFF_SH3    = 718848;     // 256 f
static constexpr size_t OFF_ASRC   = 719872;     // N*4 f
static constexpr size_t OFF_ADST   = 1519872;    // N*4 f
static constexpr size_t OFF_SRCS   = 2319872;    // E ints
static constexpr size_t OFF_Z      = 5519872;    // N*48 f
static constexpr size_t OFF_H      = 15119872;   // N*256 f
static constexpr size_t OFF_OUTP   = 66319872;   // N*256 f
static constexpr size_t OFF_POOL   = 117519872;  // G*256 f  (total ~118 MB)

#define DEV static __device__ __forceinline__

DEV float lrelu(float v) { return v > 0.f ? v : 0.2f * v; }

// ---------- 1. column sums/sumsq of x[:, :512] for bn1 ----------
__global__ void k_bn1_stats(const float* __restrict__ x, float* __restrict__ sum,
                            float* __restrict__ sq) {
    int c = threadIdx.x;                 // block 512
    float a = 0.f, b = 0.f;
    for (int r = blockIdx.x; r < N_; r += gridDim.x) {
        float v = x[r * IN_ + c];
        a += v; b += v * v;
    }
    atomicAdd(&sum[c], a);
    atomicAdd(&sq[c], b);
}

// ---------- 2. fold bn1 into Wc : Wc2[j][i]=Wc[i][j]*s1[j], c2[i]=bc+sum t1*Wc ----------
__global__ void k_fold1(const float* __restrict__ sum, const float* __restrict__ sq,
                        const float* __restrict__ g, const float* __restrict__ b,
                        const float* __restrict__ Wc, const float* __restrict__ bc,
                        float* __restrict__ Wc2, float* __restrict__ c2) {
    __shared__ float t1[512];
    int j = threadIdx.x;                 // block 512
    float mu  = sum[j] / (float)N_;
    float var = sq[j] / (float)N_ - mu * mu;
    float s   = g[j] * rsqrtf(var + EPS_);
    t1[j] = b[j] - mu * s;
    for (int i = 0; i < 16; i++) Wc2[j * 16 + i] = Wc[i * 512 + j] * s;
    __syncthreads();
    if (j < 16) {
        float acc = bc[j];
        for (int k = 0; k < 512; k++) acc += t1[k] * Wc[j * 512 + k];
        c2[j] = acc;
    }
}

// ---------- 3. z = [x_cnn(16) | layernorm(f)(32)] per node ----------
__global__ void k_z(const float* __restrict__ x, const float* __restrict__ Wc2g,
                    const float* __restrict__ c2g, const float* __restrict__ lng,
                    const float* __restrict__ lnb, float* __restrict__ z) {
    __shared__ float wc2[512 * 16];
    __shared__ float c2s[16];
    int t = threadIdx.x;                 // block 256, 16 nodes per block
    for (int q = t; q < 8192; q += 256) wc2[q] = Wc2g[q];
    if (t < 16) c2s[t] = c2g[t];
    __syncthreads();
    int nd = t >> 4, i = t & 15;
    int node = blockIdx.x * 16 + nd;     // grid 3125 -> exact
    const float4* xr = (const float4*)(x + node * IN_);
    float acc = c2s[i];
#pragma unroll 4
    for (int u = 0; u < 128; u++) {
        float4 xv = xr[u];
        int j4 = u * 4;
        acc += xv.x * wc2[(j4 + 0) * 16 + i];
        acc += xv.y * wc2[(j4 + 1) * 16 + i];
        acc += xv.z * wc2[(j4 + 2) * 16 + i];
        acc += xv.w * wc2[(j4 + 3) * 16 + i];
    }
    z[node * 48 + i] = acc;
    // layernorm over last 32 cols: this thread handles cols i and i+16
    float v1 = x[node * IN_ + 512 + i];
    float v2 = x[node * IN_ + 528 + i];
    float sm = v1 + v2, sqv = v1 * v1 + v2 * v2;
    for (int m = 1; m < 16; m <<= 1) {
        sm  += __shfl_xor(sm, m);
        sqv += __shfl_xor(sqv, m);
    }
    float mu  = sm * (1.f / 32.f);
    float var = sqv * (1.f / 32.f) - mu * mu;
    float rs  = rsqrtf(var + EPS_);
    z[node * 48 + 16 + i] = (v1 - mu) * rs * lng[i]      + lnb[i];
    z[node * 48 + 32 + i] = (v2 - mu) * rs * lng[16 + i] + lnb[16 + i];
}

// ---------- 4. column stats of z (48 cols) for bn2 ----------
__global__ void k_bn2_stats(const float* __restrict__ z, float* __restrict__ sum,
                            float* __restrict__ sq) {
    int t = threadIdx.x;                 // block 256
    int c = t & 63, rsub = t >> 6;
    float a = 0.f, b = 0.f;
    if (c < 48) {
        for (int r = blockIdx.x * 4 + rsub; r < N_; r += gridDim.x * 4) {
            float v = z[r * 48 + c];
            a += v; b += v * v;
        }
        atomicAdd(&sum[c], a);
        atomicAdd(&sq[c], b);
    }
}

// ---------- 5. fold bn2 into Wp ----------
__global__ void k_fold2(const float* __restrict__ sum, const float* __restrict__ sq,
                        const float* __restrict__ g, const float* __restrict__ b,
                        const float* __restrict__ Wp, const float* __restrict__ bp,
                        float* __restrict__ Wp2, float* __restrict__ cp) {
    __shared__ float t2[48];
    int i = threadIdx.x;                 // block 64
    if (i < 48) {
        float mu  = sum[i] / (float)N_;
        float var = sq[i] / (float)N_ - mu * mu;
        float s   = g[i] * rsqrtf(var + EPS_);
        t2[i] = b[i] - mu * s;
        for (int k = 0; k < 64; k++) Wp2[i * 64 + k] = Wp[k * 48 + i] * s;
    }
    __syncthreads();
    float acc = bp[i];
    for (int j = 0; j < 48; j++) acc += t2[j] * Wp[i * 48 + j];
    cp[i] = acc;
}

// ---------- 6. transpose Wg (256x64) -> Wgt (64x256) ----------
__global__ void k_wgt(const float* __restrict__ Wg, float* __restrict__ Wgt) {
    int idx = blockIdx.x * 256 + threadIdx.x;    // grid 64
    if (idx < 16384) {
        int c = idx >> 6, k = idx & 63;
        Wgt[k * 256 + c] = Wg[idx];
    }
}

// ---------- 7. z -> z1(relu) -> h (N x 256), plus attention logits a_src/a_dst ----------
__global__ __launch_bounds__(512) void k_h(
        const float* __restrict__ z, const float* __restrict__ Wp2g,
        const float* __restrict__ cpg, const float* __restrict__ Wgtg,
        const float* __restrict__ att_s, const float* __restrict__ att_d,
        float* __restrict__ hq, float* __restrict__ asrc, float* __restrict__ adst) {
    __shared__ __align__(16) float zl[32 * 48];
    __shared__ __align__(16) float z1l[32 * 64];
    __shared__ __align__(16) float wp2[48 * 64];
    __shared__ __align__(16) float cps[64];
    __shared__ __align__(16) float ats[256];
    __shared__ __align__(16) float atd[256];
    __shared__ __align__(16) float wgh[32 * 256];    // half of Wgt at a time
    int t = threadIdx.x;                  // block 512, 32 nodes per block
    int base = blockIdx.x * 32;
    for (int q = t; q < 3072; q += 512) wp2[q] = Wp2g[q];
    if (t < 64) cps[t] = cpg[t];
    if (t < 256) { ats[t] = att_s[t]; atd[t] = att_d[t]; }
    for (int q = t; q < 1536; q += 512) {
        int gi = base * 48 + q;
        zl[q] = (gi < N_ * 48) ? z[gi] : 0.f;
    }
    for (int q = t; q < 8192; q += 512) wgh[q] = Wgtg[q];
    __syncthreads();
    // phase 1: z1 = relu(z @ Wp2 + cp)
    for (int p = 0; p < 4; p++) {
        int idx = p * 512 + t;
        int nd = idx >> 6, l = idx & 63;
        float acc = cps[l];
        for (int j = 0; j < 48; j++) acc += zl[nd * 48 + j] * wp2[j * 64 + l];
        z1l[idx] = fmaxf(acc, 0.f);
    }
    __syncthreads();
    // phase 2: h = z1 @ Wg.T  (k split into two halves for 64KB LDS budget)
    int w = t >> 6, l = t & 63;
    int w4 = w * 4;
    float4 acc[4];
#pragma unroll
    for (int q = 0; q < 4; q++) acc[q] = make_float4(0.f, 0.f, 0.f, 0.f);
    const float4* wgh4 = (const float4*)wgh;
    for (int k = 0; k < 32; k++) {
        float4 wv = wgh4[k * 64 + l];
#pragma unroll
        for (int q = 0; q < 4; q++) {
            float zv = z1l[(w4 + q) * 64 + k];
            acc[q].x += zv * wv.x; acc[q].y += zv * wv.y;
            acc[q].z += zv * wv.z; acc[q].w += zv * wv.w;
        }
    }
    __syncthreads();
    for (int q = t; q < 8192; q += 512) wgh[q] = Wgtg[8192 + q];
    __syncthreads();
    for (int k = 32; k < 64; k++) {
        float4 wv = wgh4[(k - 32) * 64 + l];
#pragma unroll
        for (int q = 0; q < 4; q++) {
            float zv = z1l[(w4 + q) * 64 + k];
            acc[q].x += zv * wv.x; acc[q].y += zv * wv.y;
            acc[q].z += zv * wv.z; acc[q].w += zv * wv.w;
        }
    }
    float4 as4 = ((const float4*)ats)[l];
    float4 ad4 = ((const float4*)atd)[l];
    float4* h4 = (float4*)hq;
#pragma unroll
    for (int q = 0; q < 4; q++) {
        int node = base + w4 + q;
        if (node < N_) {
            h4[node * 64 + l] = acc[q];
            float pa = acc[q].x * as4.x + acc[q].y * as4.y + acc[q].z * as4.z + acc[q].w * as4.w;
            float pb = acc[q].x * ad4.x + acc[q].y * ad4.y + acc[q].z * ad4.z + acc[q].w * ad4.w;
            for (int m = 1; m < 16; m <<= 1) {
                pa += __shfl_xor(pa, m);
                pb += __shfl_xor(pb, m);
            }
            if ((l & 15) == 0) {
                asrc[node * 4 + (l >> 4)] = pa;
                adst[node * 4 + (l >> 4)] = pb;
            }
        }
    }
}

// ---------- 8. edge histogram by dst ----------
__global__ void k_hist(const int* __restrict__ ei, int* __restrict__ count) {
    int k = blockIdx.x * 256 + threadIdx.x;      // grid 3125 -> exact
    atomicAdd(&count[ei[E_ + k]], 1);
}

// ---------- 9. three-phase exclusive scan of count -> offsets ----------
__global__ void k_scan1(const int* __restrict__ count, int* __restrict__ offs,
                        int* __restrict__ part) {
    __shared__ int sd[1024];
    int t = threadIdx.x;
    int idx = blockIdx.x * 1024 + t;
    int v = (idx < N_) ? count[idx] : 0;
    sd[t] = v;
    for (int off = 1; off < 1024; off <<= 1) {
        __syncthreads();
        int tmp = (t >= off) ? sd[t - off] : 0;
        __syncthreads();
        sd[t] += tmp;
    }
    if (idx < N_) offs[idx] = sd[t] - v;
    if (t == 1023) part[blockIdx.x] = sd[1023];
}
__global__ void k_scan2(int* __restrict__ part, int nb) {
    if (threadIdx.x == 0) {
        int run = 0;
        for (int i = 0; i < nb; i++) { int tv = part[i]; part[i] = run; run += tv; }
    }
}
__global__ void k_scan3(int* __restrict__ offs, const int* __restrict__ part) {
    int idx = blockIdx.x * 1024 + threadIdx.x;
    if (idx < N_) offs[idx] += part[blockIdx.x];
}

// ---------- 10. scatter edges into dst-CSR ----------
__global__ void k_scatter(const int* __restrict__ ei, const int* __restrict__ offs,
                          int* __restrict__ cur, int* __restrict__ srcsort) {
    int k = blockIdx.x * 256 + threadIdx.x;
    int src = ei[k], dst = ei[E_ + k];
    int pos = offs[dst] + atomicAdd(&cur[dst], 1);
    srcsort[pos] = src;
}

// ---------- 11. per-dst softmax attention aggregation (wave per node) ----------
__global__ __launch_bounds__(256) void k_agg(
        const int* __restrict__ count, const int* __restrict__ offs,
        const int* __restrict__ srcsort, const float* __restrict__ asrc,
        const float* __restrict__ adst, const float* __restrict__ hq,
        const float* __restrict__ bg, float* __restrict__ outpre) {
    int w = threadIdx.x >> 6, l = threadIdx.x & 63;
    int dst = blockIdx.x * 4 + w;                 // grid 12500 -> exact
    const float4* asrc4 = (const float4*)asrc;
    const float4* h4    = (const float4*)hq;
    float4* out4 = (float4*)outpre;
    float4 bgv = ((const float4*)bg)[l];
    int deg = count[dst];
    if (deg == 0) { out4[dst * 64 + l] = bgv; return; }
    int base = offs[dst];
    float4 ad = ((const float4*)adst)[dst];
    const float NEGINF = -__builtin_inff();
    // pass A: per-lane strips, reduce max
    int my_src = 0;
    float4 my_e = make_float4(NEGINF, NEGINF, NEGINF, NEGINF);
    if (l < deg) {
        my_src = srcsort[base + l];
        float4 a = asrc4[my_src];
        my_e = make_float4(lrelu(a.x + ad.x), lrelu(a.y + ad.y),
                           lrelu(a.z + ad.z), lrelu(a.w + ad.w));
    }
    float4 mx = my_e;
    for (int j = l + 64; j < deg; j += 64) {
        int s2 = srcsort[base + j];
        float4 a = asrc4[s2];
        mx.x = fmaxf(mx.x, lrelu(a.x + ad.x)); mx.y = fmaxf(mx.y, lrelu(a.y + ad.y));
        mx.z = fmaxf(mx.z, lrelu(a.z + ad.z)); mx.w = fmaxf(mx.w, lrelu(a.w + ad.w));
    }
    for (int m = 1; m < 64; m <<= 1) {
        mx.x = fmaxf(mx.x, __shfl_xor(mx.x, m));
        mx.y = fmaxf(mx.y, __shfl_xor(mx.y, m));
        mx.z = fmaxf(mx.z, __shfl_xor(mx.z, m));
        mx.w = fmaxf(mx.w, __shfl_xor(mx.w, m));
    }
    // pass B: sum of exp
    float4 sv = make_float4(0.f, 0.f, 0.f, 0.f);
    if (l < deg) {
        sv.x = __expf(my_e.x - mx.x); sv.y = __expf(my_e.y - mx.y);
        sv.z = __expf(my_e.z - mx.z); sv.w = __expf(my_e.w - mx.w);
    }
    for (int j = l + 64; j < deg; j += 64) {
        int s2 = srcsort[base + j];
        float4 a = asrc4[s2];
        sv.x += __expf(lrelu(a.x + ad.x) - mx.x);
        sv.y += __expf(lrelu(a.y + ad.y) - mx.y);
        sv.z += __expf(lrelu(a.z + ad.z) - mx.z);
        sv.w += __expf(lrelu(a.w + ad.w) - mx.w);
    }
    for (int m = 1; m < 64; m <<= 1) {
        sv.x += __shfl_xor(sv.x, m); sv.y += __shfl_xor(sv.y, m);
        sv.z += __shfl_xor(sv.z, m); sv.w += __shfl_xor(sv.w, m);
    }
    int hd = l >> 4;
    float mh  = hd == 0 ? mx.x : hd == 1 ? mx.y : hd == 2 ? mx.z : mx.w;
    float sh  = hd == 0 ? sv.x : hd == 1 ? sv.y : hd == 2 ? sv.z : sv.w;
    float adh = hd == 0 ? ad.x : hd == 1 ? ad.y : hd == 2 ? ad.z : ad.w;
    float inv = 1.f / fmaxf(sh, 1e-16f);
    float4 acc = make_float4(0.f, 0.f, 0.f, 0.f);
    for (int j = 0; j < deg; j++) {
        int src; float eh;
        if (j < 64) {
            src = __shfl(my_src, j);
            float ex_ = __shfl(my_e.x, j), ey_ = __shfl(my_e.y, j);
            float ez_ = __shfl(my_e.z, j), ew_ = __shfl(my_e.w, j);
            eh = hd == 0 ? ex_ : hd == 1 ? ey_ : hd == 2 ? ez_ : ew_;
        } else {
            src = srcsort[base + j];
            float4 a = asrc4[src];
            float ah = hd == 0 ? a.x : hd == 1 ? a.y : hd == 2 ? a.z : a.w;
            eh = lrelu(ah + adh);
        }
        float wgt = __expf(eh - mh) * inv;
        float4 hv = h4[src * 64 + l];
        acc.x += wgt * hv.x; acc.y += wgt * hv.y;
        acc.z += wgt * hv.z; acc.w += wgt * hv.w;
    }
    out4[dst * 64 + l] = make_float4(acc.x + bgv.x, acc.y + bgv.y,
                                     acc.z + bgv.z, acc.w + bgv.w);
}

// ---------- 12. column stats of outpre (256 cols) for bn3 ----------
__global__ void k_bn3_stats(const float* __restrict__ op, float* __restrict__ sum,
                            float* __restrict__ sq) {
    int c = threadIdx.x;                 // block 256
    float a = 0.f, b = 0.f;
    for (int r = blockIdx.x; r < N_; r += gridDim.x) {
        float v = op[r * 256 + c];
        a += v; b += v * v;
    }
    atomicAdd(&sum[c], a);
    atomicAdd(&sq[c], b);
}

__global__ void k_fold3(const float* __restrict__ sum, const float* __restrict__ sq,
                        const float* __restrict__ g, const float* __restrict__ b,
                        float* __restrict__ sc, float* __restrict__ sh) {
    int c = threadIdx.x;                 // block 256
    float mu  = sum[c] / (float)N_;
    float var = sq[c] / (float)N_ - mu * mu;
    float s   = g[c] * rsqrtf(var + EPS_);
    sc[c] = s;
    sh[c] = b[c] - mu * s;
}

// ---------- 13. graph mean-pool of elu(bn3(outpre)), one block per graph ----------
__global__ void k_pool(const float* __restrict__ op, const int* __restrict__ batch,
                       const float* __restrict__ sc, const float* __restrict__ sh,
                       float* __restrict__ pooled) {
    int g = blockIdx.x;                  // grid 512, block 256
    int t = threadIdx.x;
    int lo = 0, hi = N_;
    while (lo < hi) { int mid = (lo + hi) >> 1; if (batch[mid] < g) lo = mid + 1; else hi = mid; }
    int start = lo;
    hi = N_;
    while (lo < hi) { int mid = (lo + hi) >> 1; if (batch[mid] < g + 1) lo = mid + 1; else hi = mid; }
    int end = lo;
    float scv = sc[t], shv = sh[t];
    float acc = 0.f;
    for (int n = start; n < end; n++) {
        float v = op[n * 256 + t] * scv + shv;
        acc += (v > 0.f) ? v : expm1f(v);
    }
    float cn = (float)(end - start);
    pooled[g * 256 + t] = acc / fmaxf(cn, 1.f);
}

// ---------- 14. final MLP: relu(pooled@W1.T+b1) @ W2.T + b2 ----------
__global__ void k_mlp(const float* __restrict__ pooled, const float* __restrict__ W1,
                      const float* __restrict__ b1, const float* __restrict__ W2,
                      const float* __restrict__ b2, float* __restrict__ out) {
    __shared__ float pl[256];
    __shared__ float hm[64];
    int g = blockIdx.x;                  // grid 512, block 64
    int i = threadIdx.x;
    for (int q = i; q < 256; q += 64) pl[q] = pooled[g * 256 + q];
    __syncthreads();
    float acc = b1[i];
    for (int c = 0; c < 256; c++) acc += pl[c] * W1[i * 256 + c];
    hm[i] = fmaxf(acc, 0.f);
    __syncthreads();
    if (i < 2) {
        float a = b2[i];
        for (int k = 0; k < 64; k++) a += hm[k] * W2[i * 64 + k];
        out[g * 2 + i] = a;
    }
}

extern "C" void kernel_launch(void* const* d_in, const int* in_sizes, int n_in,
                              void* d_out, int out_size, void* d_ws, size_t ws_size,
                              hipStream_t stream) {
    const float* x    = (const float*)d_in[0];
    const int*   ei   = (const int*)d_in[1];
    const int*   batch= (const int*)d_in[2];
    const float* lng  = (const float*)d_in[3];
    const float* lnb  = (const float*)d_in[4];
    const float* bn1g = (const float*)d_in[5];
    const float* bn1b = (const float*)d_in[6];
    const float* Wc   = (const float*)d_in[7];
    const float* bc   = (const float*)d_in[8];
    const float* bn2g = (const float*)d_in[9];
    const float* bn2b = (const float*)d_in[10];
    const float* Wp   = (const float*)d_in[11];
    const float* bp   = (const float*)d_in[12];
    const float* Wg   = (const float*)d_in[13];
    const float* atts = (const float*)d_in[14];
    const float* attd = (const float*)d_in[15];
    const float* bg   = (const float*)d_in[16];
    const float* bn3g = (const float*)d_in[17];
    const float* bn3b = (const float*)d_in[18];
    const float* W1   = (const float*)d_in[19];
    const float* b1   = (const float*)d_in[20];
    const float* W2   = (const float*)d_in[21];
    const float* b2   = (const float*)d_in[22];
    float* out = (float*)d_out;

    char* w8 = (char*)d_ws;
    float* bn1sum = (float*)(w8 + OFF_BN1SUM);
    float* bn1sq  = (float*)(w8 + OFF_BN1SQ);
    float* bn2sum = (float*)(w8 + OFF_BN2SUM);
    float* bn2sq  = (float*)(w8 + OFF_BN2SQ);
    float* bn3sum = (float*)(w8 + OFF_BN3SUM);
    float* bn3sq  = (float*)(w8 + OFF_BN3SQ);
    int*   count  = (int*)(w8 + OFF_COUNT);
    int*   cur    = (int*)(w8 + OFF_CUR);
    int*   offs   = (int*)(w8 + OFF_OFFS);
    int*   part   = (int*)(w8 + OFF_PART);
    float* Wc2    = (float*)(w8 + OFF_WC2);
    float* c2     = (float*)(w8 + OFF_C2);
    float* Wp2    = (float*)(w8 + OFF_WP2);
    float* cp     = (float*)(w8 + OFF_CP);
    float* Wgt    = (float*)(w8 + OFF_WGT);
    float* sc3    = (float*)(w8 + OFF_SC3);
    float* sh3    = (float*)(w8 + OFF_SH3);
    float* asrc   = (float*)(w8 + OFF_ASRC);
    float* adst   = (float*)(w8 + OFF_ADST);
    int*   srcs   = (int*)(w8 + OFF_SRCS);
    float* z      = (float*)(w8 + OFF_Z);
    float* h      = (float*)(w8 + OFF_H);
    float* outp   = (float*)(w8 + OFF_OUTP);
    float* pooled = (float*)(w8 + OFF_POOL);

    hipMemsetAsync(d_ws, 0, ZERO_BYTES, stream);

    k_bn1_stats<<<256, 512, 0, stream>>>(x, bn1sum, bn1sq);
    k_fold1<<<1, 512, 0, stream>>>(bn1sum, bn1sq, bn1g, bn1b, Wc, bc, Wc2, c2);
    k_z<<<N_ / 16, 256, 0, stream>>>(x, Wc2, c2, lng, lnb, z);
    k_bn2_stats<<<512, 256, 0, stream>>>(z, bn2sum, bn2sq);
    k_fold2<<<1, 64, 0, stream>>>(bn2sum, bn2sq, bn2g, bn2b, Wp, bp, Wp2, cp);
    k_wgt<<<64, 256, 0, stream>>>(Wg, Wgt);
    k_h<<<(N_ + 31) / 32, 512, 0, stream>>>(z, Wp2, cp, Wgt, atts, attd, h, asrc, adst);
    k_hist<<<E_ / 256, 256, 0, stream>>>(ei, count);
    const int SCANB = (N_ + 1023) / 1024;
    k_scan1<<<SCANB, 1024, 0, stream>>>(count, offs, part);
    k_scan2<<<1, 64, 0, stream>>>(part, SCANB);
    k_scan3<<<SCANB, 1024, 0, stream>>>(offs, part);
    k_scatter<<<E_ / 256, 256, 0, stream>>>(ei, offs, cur, srcs);
    k_agg<<<N_ / 4, 256, 0, stream>>>(count, offs, srcs, asrc, adst, h, bg, outp);
    k_bn3_stats<<<256, 256, 0, stream>>>(outp, bn3sum, bn3sq);
    k_fold3<<<1, 256, 0, stream>>>(bn3sum, bn3sq, bn3g, bn3b, sc3, sh3);
    k_pool<<<G_, 256, 0, stream>>>(outp, batch, sc3, sh3, pooled);
    k_mlp<<<G_, 64, 0, stream>>>(pooled, W1, b1, W2, b2, out);
}

// Round 2
// 770.890 us; speedup vs baseline: 1.7103x; 1.7103x over previous
//
#include <hip/hip_runtime.h>

static constexpr int N_   = 50000;
static constexpr int E_   = 800000;
static constexpr int G_   = 512;
static constexpr int IN_  = 544;
static constexpr float EPS_ = 1e-5f;

// ---------------- workspace byte offsets ----------------
static constexpr size_t OFF_BN1SUM = 0;          // 512 f
static constexpr size_t OFF_BN1SQ  = 2048;       // 512 f
static constexpr size_t OFF_BN2SUM = 4096;       // 48 f
static constexpr size_t OFF_BN2SQ  = 4288;       // 48 f
static constexpr size_t OFF_BN3SUM = 4480;       // 256 f
static constexpr size_t OFF_BN3SQ  = 5504;       // 256 f
static constexpr size_t OFF_COUNT  = 6528;       // N ints
static constexpr size_t OFF_CUR    = 206528;     // N ints
static constexpr size_t ZERO_BYTES = 406528;     // one memset covers all of the above
static constexpr size_t OFF_OFFS   = 406528;     // N ints
static constexpr size_t OFF_PART   = 606592;     // 64 ints
static constexpr size_t OFF_WC2    = 606848;     // 512*16 f
static constexpr size_t OFF_C2     = 639616;     // 16 f
static constexpr size_t OFF_WP2    = 639744;     // 48*64 f
static constexpr size_t OFF_CP     = 652032;     // 64 f
static constexpr size_t OFF_WGT    = 652288;     // 64*256 f
static constexpr size_t OFF_SC3    = 717824;     // 256 f
static constexpr size_t OFF_SH3    = 718848;     // 256 f
static constexpr size_t OFF_ASRC   = 719872;     // N*4 f
static constexpr size_t OFF_ADST   = 1519872;    // N*4 f
static constexpr size_t OFF_SRCS   = 2319872;    // E ints
static constexpr size_t OFF_Z      = 5519872;    // N*48 f
static constexpr size_t OFF_H      = 15119872;   // N*256 f
static constexpr size_t OFF_OUTP   = 66319872;   // N*256 f
// z1 (N*64 f = 12.8 MB) overlaps OUTP: z1 is dead before k_agg writes outp.
static constexpr size_t OFF_Z1     = 66319872;
static constexpr size_t OFF_POOL   = 117519872;  // G*256 f  (total ~118 MB)

#define DEV static __device__ __forceinline__

DEV float lrelu(float v) { return v > 0.f ? v : 0.2f * v; }

// ---------- 1. column sums/sumsq of x[:, :512] for bn1 ----------
__global__ void k_bn1_stats(const float* __restrict__ x, float* __restrict__ sum,
                            float* __restrict__ sq) {
    int c = threadIdx.x;                 // block 512
    float a = 0.f, b = 0.f;
    for (int r = blockIdx.x; r < N_; r += gridDim.x) {
        float v = x[r * IN_ + c];
        a += v; b += v * v;
    }
    atomicAdd(&sum[c], a);
    atomicAdd(&sq[c], b);
}

// ---------- 2. fold bn1 into Wc ----------
__global__ void k_fold1(const float* __restrict__ sum, const float* __restrict__ sq,
                        const float* __restrict__ g, const float* __restrict__ b,
                        const float* __restrict__ Wc, const float* __restrict__ bc,
                        float* __restrict__ Wc2, float* __restrict__ c2) {
    __shared__ float t1[512];
    int j = threadIdx.x;                 // block 512
    float mu  = sum[j] / (float)N_;
    float var = sq[j] / (float)N_ - mu * mu;
    float s   = g[j] * rsqrtf(var + EPS_);
    t1[j] = b[j] - mu * s;
    for (int i = 0; i < 16; i++) Wc2[j * 16 + i] = Wc[i * 512 + j] * s;
    __syncthreads();
    if (j < 16) {
        float acc = bc[j];
        for (int k = 0; k < 512; k++) acc += t1[k] * Wc[j * 512 + k];
        c2[j] = acc;
    }
}

// ---------- 3. z = [x_cnn(16) | layernorm(f)(32)] : 64 nodes/block ----------
__global__ __launch_bounds__(512) void k_z(
        const float* __restrict__ x, const float* __restrict__ Wc2g,
        const float* __restrict__ c2g, const float* __restrict__ lng,
        const float* __restrict__ lnb, float* __restrict__ z) {
    __shared__ float wc2[512 * 16];      // 32 KB, amortized over 64 nodes
    __shared__ float c2s[16];
    int t = threadIdx.x;
    for (int q = t; q < 8192; q += 512) wc2[q] = Wc2g[q];
    if (t < 16) c2s[t] = c2g[t];
    __syncthreads();
    int nd = t >> 3, i = t & 7;          // 8 threads per node, 2 cols each
    int node = blockIdx.x * 64 + nd;     // grid 782
    if (node >= N_) return;              // wave-uniform guard (8-lane groups never straddle)
    const float4* xr = (const float4*)(x + node * IN_);
    float acc0 = c2s[i], acc1 = c2s[i + 8];
    for (int u = 0; u < 128; u++) {
        float4 xv = xr[u];
        int j4 = u * 4;
        acc0 += xv.x * wc2[(j4 + 0) * 16 + i];
        acc0 += xv.y * wc2[(j4 + 1) * 16 + i];
        acc0 += xv.z * wc2[(j4 + 2) * 16 + i];
        acc0 += xv.w * wc2[(j4 + 3) * 16 + i];
        acc1 += xv.x * wc2[(j4 + 0) * 16 + i + 8];
        acc1 += xv.y * wc2[(j4 + 1) * 16 + i + 8];
        acc1 += xv.z * wc2[(j4 + 2) * 16 + i + 8];
        acc1 += xv.w * wc2[(j4 + 3) * 16 + i + 8];
    }
    z[node * 48 + i]     = acc0;
    z[node * 48 + i + 8] = acc1;
    // layernorm over last 32 cols: this thread handles cols 512 + i + 8*jj
    float v[4]; float sm = 0.f, sqv = 0.f;
#pragma unroll
    for (int jj = 0; jj < 4; jj++) {
        v[jj] = x[node * IN_ + 512 + i + 8 * jj];
        sm += v[jj]; sqv += v[jj] * v[jj];
    }
    for (int m = 1; m < 8; m <<= 1) {
        sm  += __shfl_xor(sm, m);
        sqv += __shfl_xor(sqv, m);
    }
    float mu  = sm * (1.f / 32.f);
    float var = sqv * (1.f / 32.f) - mu * mu;
    float rs  = rsqrtf(var + EPS_);
#pragma unroll
    for (int jj = 0; jj < 4; jj++) {
        int c = i + 8 * jj;
        z[node * 48 + 16 + c] = (v[jj] - mu) * rs * lng[c] + lnb[c];
    }
}

// ---------- 4. column stats of z (48 cols) for bn2 ----------
__global__ void k_bn2_stats(const float* __restrict__ z, float* __restrict__ sum,
                            float* __restrict__ sq) {
    int t = threadIdx.x;                 // block 256
    int c = t & 63, rsub = t >> 6;
    float a = 0.f, b = 0.f;
    if (c < 48) {
        for (int r = blockIdx.x * 4 + rsub; r < N_; r += gridDim.x * 4) {
            float v = z[r * 48 + c];
            a += v; b += v * v;
        }
        atomicAdd(&sum[c], a);
        atomicAdd(&sq[c], b);
    }
}

// ---------- 5. fold bn2 into Wp ----------
__global__ void k_fold2(const float* __restrict__ sum, const float* __restrict__ sq,
                        const float* __restrict__ g, const float* __restrict__ b,
                        const float* __restrict__ Wp, const float* __restrict__ bp,
                        float* __restrict__ Wp2, float* __restrict__ cp) {
    __shared__ float t2[48];
    int i = threadIdx.x;                 // block 64
    if (i < 48) {
        float mu  = sum[i] / (float)N_;
        float var = sq[i] / (float)N_ - mu * mu;
        float s   = g[i] * rsqrtf(var + EPS_);
        t2[i] = b[i] - mu * s;
        for (int k = 0; k < 64; k++) Wp2[i * 64 + k] = Wp[k * 48 + i] * s;
    }
    __syncthreads();
    float acc = bp[i];
    for (int j = 0; j < 48; j++) acc += t2[j] * Wp[i * 48 + j];
    cp[i] = acc;
}

// ---------- 6. transpose Wg (256x64) -> Wgt (64x256) ----------
__global__ void k_wgt(const float* __restrict__ Wg, float* __restrict__ Wgt) {
    int idx = blockIdx.x * 256 + threadIdx.x;    // grid 64
    if (idx < 16384) {
        int c = idx >> 6, k = idx & 63;
        Wgt[k * 256 + c] = Wg[idx];
    }
}

// ---------- 7a. z1 = relu(z @ Wp2 + cp) : one wave per node ----------
__global__ __launch_bounds__(256) void k_h1(
        const float* __restrict__ z, const float* __restrict__ Wp2g,
        const float* __restrict__ cpg, float* __restrict__ z1) {
    __shared__ float wp2[48 * 64];       // 12 KB
    __shared__ float cps[64];
    int t = threadIdx.x;
    for (int q = t; q < 3072; q += 256) wp2[q] = Wp2g[q];
    if (t < 64) cps[t] = cpg[t];
    __syncthreads();
    int wid = (blockIdx.x * 256 + t) >> 6;
    int l = t & 63;
    int nwaves = gridDim.x * 4;
    for (int node = wid; node < N_; node += nwaves) {
        const float4* zr4 = (const float4*)(z + node * 48);
        float acc = cps[l];
#pragma unroll
        for (int u = 0; u < 12; u++) {
            float4 zv = zr4[u];
            int j4 = u * 4;
            acc += zv.x * wp2[(j4 + 0) * 64 + l];
            acc += zv.y * wp2[(j4 + 1) * 64 + l];
            acc += zv.z * wp2[(j4 + 2) * 64 + l];
            acc += zv.w * wp2[(j4 + 3) * 64 + l];
        }
        z1[node * 64 + l] = fmaxf(acc, 0.f);
    }
}

// ---------- 7b. h = z1 @ Wg.T + attention logits : 128 nodes/block ----------
__global__ __launch_bounds__(512) void k_h2(
        const float* __restrict__ z1, const float* __restrict__ Wgtg,
        const float* __restrict__ att_s, const float* __restrict__ att_d,
        float* __restrict__ hq, float* __restrict__ asrc, float* __restrict__ adst) {
    __shared__ float4 wgh[32 * 64];      // half of Wgt: 32 KB
    __shared__ float  z1t[128 * 64];     // 32 KB node tile
    __shared__ float4 ats[64];
    __shared__ float4 atd[64];
    int t = threadIdx.x;                 // block 512, grid 391
    int base = blockIdx.x * 128;
    // stage z1 tile (last block reads past row N_ into slack; results discarded)
    {
        const float4* z14 = (const float4*)(z1 + (size_t)base * 64);
        float4* z1t4 = (float4*)z1t;
        for (int q = t; q < 2048; q += 512) z1t4[q] = z14[q];
    }
    if (t < 64) {
        ats[t] = ((const float4*)att_s)[t];
        atd[t] = ((const float4*)att_d)[t];
    }
    const float4* wg4 = (const float4*)Wgtg;
    int w = t >> 6, l = t & 63;          // 8 waves, 16 nodes each
    float4 acc[16];
#pragma unroll
    for (int nd = 0; nd < 16; nd++) acc[nd] = make_float4(0.f, 0.f, 0.f, 0.f);
    for (int half = 0; half < 2; half++) {
        __syncthreads();                 // protects z1t (1st) / wgh reuse (2nd)
        for (int q = t; q < 2048; q += 512) wgh[q] = wg4[half * 2048 + q];
        __syncthreads();
        int kbase = half * 32;
        for (int kk = 0; kk < 32; kk++) {
            float4 wv = wgh[kk * 64 + l];
            int k = kbase + kk;
#pragma unroll
            for (int nd = 0; nd < 16; nd++) {
                float zv = z1t[(w * 16 + nd) * 64 + k];
                acc[nd].x += zv * wv.x; acc[nd].y += zv * wv.y;
                acc[nd].z += zv * wv.z; acc[nd].w += zv * wv.w;
            }
        }
    }
    float4 as4 = ats[l], ad4 = atd[l];
    float4* h4 = (float4*)hq;
#pragma unroll
    for (int nd = 0; nd < 16; nd++) {
        int node = base + w * 16 + nd;   // wave-uniform
        if (node < N_) {
            h4[node * 64 + l] = acc[nd];
            float pa = acc[nd].x * as4.x + acc[nd].y * as4.y +
                       acc[nd].z * as4.z + acc[nd].w * as4.w;
            float pb = acc[nd].x * ad4.x + acc[nd].y * ad4.y +
                       acc[nd].z * ad4.z + acc[nd].w * ad4.w;
            for (int m = 1; m < 16; m <<= 1) {
                pa += __shfl_xor(pa, m);
                pb += __shfl_xor(pb, m);
            }
            if ((l & 15) == 0) {
                asrc[node * 4 + (l >> 4)] = pa;
                adst[node * 4 + (l >> 4)] = pb;
            }
        }
    }
}

// ---------- 8. edge histogram by dst ----------
__global__ void k_hist(const int* __restrict__ ei, int* __restrict__ count) {
    int k = blockIdx.x * 256 + threadIdx.x;      // grid 3125 -> exact
    atomicAdd(&count[ei[E_ + k]], 1);
}

// ---------- 9. three-phase exclusive scan of count -> offsets ----------
__global__ void k_scan1(const int* __restrict__ count, int* __restrict__ offs,
                        int* __restrict__ part) {
    __shared__ int sd[1024];
    int t = threadIdx.x;
    int idx = blockIdx.x * 1024 + t;
    int v = (idx < N_) ? count[idx] : 0;
    sd[t] = v;
    for (int off = 1; off < 1024; off <<= 1) {
        __syncthreads();
        int tmp = (t >= off) ? sd[t - off] : 0;
        __syncthreads();
        sd[t] += tmp;
    }
    if (idx < N_) offs[idx] = sd[t] - v;
    if (t == 1023) part[blockIdx.x] = sd[1023];
}
__global__ void k_scan2(int* __restrict__ part, int nb) {
    if (threadIdx.x == 0) {
        int run = 0;
        for (int i = 0; i < nb; i++) { int tv = part[i]; part[i] = run; run += tv; }
    }
}
__global__ void k_scan3(int* __restrict__ offs, const int* __restrict__ part) {
    int idx = blockIdx.x * 1024 + threadIdx.x;
    if (idx < N_) offs[idx] += part[blockIdx.x];
}

// ---------- 10. scatter edges into dst-CSR ----------
__global__ void k_scatter(const int* __restrict__ ei, const int* __restrict__ offs,
                          int* __restrict__ cur, int* __restrict__ srcsort) {
    int k = blockIdx.x * 256 + threadIdx.x;
    int src = ei[k], dst = ei[E_ + k];
    int pos = offs[dst] + atomicAdd(&cur[dst], 1);
    srcsort[pos] = src;
}

// ---------- 11. per-dst softmax attention aggregation (wave per node) ----------
__global__ __launch_bounds__(256) void k_agg(
        const int* __restrict__ count, const int* __restrict__ offs,
        const int* __restrict__ srcsort, const float* __restrict__ asrc,
        const float* __restrict__ adst, const float* __restrict__ hq,
        const float* __restrict__ bg, float* __restrict__ outpre) {
    int w = threadIdx.x >> 6, l = threadIdx.x & 63;
    int dst = blockIdx.x * 4 + w;                 // grid 12500 -> exact
    const float4* asrc4 = (const float4*)asrc;
    const float4* h4    = (const float4*)hq;
    float4* out4 = (float4*)outpre;
    float4 bgv = ((const float4*)bg)[l];
    int deg = count[dst];
    if (deg == 0) { out4[dst * 64 + l] = bgv; return; }
    int base = offs[dst];
    float4 ad = ((const float4*)adst)[dst];
    const float NEGINF = -__builtin_inff();
    int my_src = 0;
    float4 my_e = make_float4(NEGINF, NEGINF, NEGINF, NEGINF);
    if (l < deg) {
        my_src = srcsort[base + l];
        float4 a = asrc4[my_src];
        my_e = make_float4(lrelu(a.x + ad.x), lrelu(a.y + ad.y),
                           lrelu(a.z + ad.z), lrelu(a.w + ad.w));
    }
    float4 mx = my_e;
    for (int j = l + 64; j < deg; j += 64) {
        int s2 = srcsort[base + j];
        float4 a = asrc4[s2];
        mx.x = fmaxf(mx.x, lrelu(a.x + ad.x)); mx.y = fmaxf(mx.y, lrelu(a.y + ad.y));
        mx.z = fmaxf(mx.z, lrelu(a.z + ad.z)); mx.w = fmaxf(mx.w, lrelu(a.w + ad.w));
    }
    for (int m = 1; m < 64; m <<= 1) {
        mx.x = fmaxf(mx.x, __shfl_xor(mx.x, m));
        mx.y = fmaxf(mx.y, __shfl_xor(mx.y, m));
        mx.z = fmaxf(mx.z, __shfl_xor(mx.z, m));
        mx.w = fmaxf(mx.w, __shfl_xor(mx.w, m));
    }
    float4 sv = make_float4(0.f, 0.f, 0.f, 0.f);
    if (l < deg) {
        sv.x = __expf(my_e.x - mx.x); sv.y = __expf(my_e.y - mx.y);
        sv.z = __expf(my_e.z - mx.z); sv.w = __expf(my_e.w - mx.w);
    }
    for (int j = l + 64; j < deg; j += 64) {
        int s2 = srcsort[base + j];
        float4 a = asrc4[s2];
        sv.x += __expf(lrelu(a.x + ad.x) - mx.x);
        sv.y += __expf(lrelu(a.y + ad.y) - mx.y);
        sv.z += __expf(lrelu(a.z + ad.z) - mx.z);
        sv.w += __expf(lrelu(a.w + ad.w) - mx.w);
    }
    for (int m = 1; m < 64; m <<= 1) {
        sv.x += __shfl_xor(sv.x, m); sv.y += __shfl_xor(sv.y, m);
        sv.z += __shfl_xor(sv.z, m); sv.w += __shfl_xor(sv.w, m);
    }
    int hd = l >> 4;
    float mh  = hd == 0 ? mx.x : hd == 1 ? mx.y : hd == 2 ? mx.z : mx.w;
    float sh  = hd == 0 ? sv.x : hd == 1 ? sv.y : hd == 2 ? sv.z : sv.w;
    float adh = hd == 0 ? ad.x : hd == 1 ? ad.y : hd == 2 ? ad.z : ad.w;
    float inv = 1.f / fmaxf(sh, 1e-16f);
    float4 acc = make_float4(0.f, 0.f, 0.f, 0.f);
    for (int j = 0; j < deg; j++) {
        int src; float eh;
        if (j < 64) {
            src = __shfl(my_src, j);
            float ex_ = __shfl(my_e.x, j), ey_ = __shfl(my_e.y, j);
            float ez_ = __shfl(my_e.z, j), ew_ = __shfl(my_e.w, j);
            eh = hd == 0 ? ex_ : hd == 1 ? ey_ : hd == 2 ? ez_ : ew_;
        } else {
            src = srcsort[base + j];
            float4 a = asrc4[src];
            float ah = hd == 0 ? a.x : hd == 1 ? a.y : hd == 2 ? a.z : a.w;
            eh = lrelu(ah + adh);
        }
        float wgt = __expf(eh - mh) * inv;
        float4 hv = h4[src * 64 + l];
        acc.x += wgt * hv.x; acc.y += wgt * hv.y;
        acc.z += wgt * hv.z; acc.w += wgt * hv.w;
    }
    out4[dst * 64 + l] = make_float4(acc.x + bgv.x, acc.y + bgv.y,
                                     acc.z + bgv.z, acc.w + bgv.w);
}

// ---------- 12. column stats of outpre (256 cols) for bn3 ----------
__global__ void k_bn3_stats(const float* __restrict__ op, float* __restrict__ sum,
                            float* __restrict__ sq) {
    int c = threadIdx.x;                 // block 256
    float a = 0.f, b = 0.f;
    for (int r = blockIdx.x; r < N_; r += gridDim.x) {
        float v = op[r * 256 + c];
        a += v; b += v * v;
    }
    atomicAdd(&sum[c], a);
    atomicAdd(&sq[c], b);
}

__global__ void k_fold3(const float* __restrict__ sum, const float* __restrict__ sq,
                        const float* __restrict__ g, const float* __restrict__ b,
                        float* __restrict__ sc, float* __restrict__ sh) {
    int c = threadIdx.x;                 // block 256
    float mu  = sum[c] / (float)N_;
    float var = sq[c] / (float)N_ - mu * mu;
    float s   = g[c] * rsqrtf(var + EPS_);
    sc[c] = s;
    sh[c] = b[c] - mu * s;
}

// ---------- 13. graph mean-pool of elu(bn3(outpre)) ----------
__global__ void k_pool(const float* __restrict__ op, const int* __restrict__ batch,
                       const float* __restrict__ sc, const float* __restrict__ sh,
                       float* __restrict__ pooled) {
    int g = blockIdx.x;                  // grid 512, block 256
    int t = threadIdx.x;
    int lo = 0, hi = N_;
    while (lo < hi) { int mid = (lo + hi) >> 1; if (batch[mid] < g) lo = mid + 1; else hi = mid; }
    int start = lo;
    hi = N_;
    while (lo < hi) { int mid = (lo + hi) >> 1; if (batch[mid] < g + 1) lo = mid + 1; else hi = mid; }
    int end = lo;
    float scv = sc[t], shv = sh[t];
    float acc = 0.f;
    for (int n = start; n < end; n++) {
        float v = op[n * 256 + t] * scv + shv;
        acc += (v > 0.f) ? v : expm1f(v);
    }
    float cn = (float)(end - start);
    pooled[g * 256 + t] = acc / fmaxf(cn, 1.f);
}

// ---------- 14. final MLP ----------
__global__ void k_mlp(const float* __restrict__ pooled, const float* __restrict__ W1,
                      const float* __restrict__ b1, const float* __restrict__ W2,
                      const float* __restrict__ b2, float* __restrict__ out) {
    __shared__ float pl[256];
    __shared__ float hm[64];
    int g = blockIdx.x;                  // grid 512, block 64
    int i = threadIdx.x;
    for (int q = i; q < 256; q += 64) pl[q] = pooled[g * 256 + q];
    __syncthreads();
    float acc = b1[i];
    for (int c = 0; c < 256; c++) acc += pl[c] * W1[i * 256 + c];
    hm[i] = fmaxf(acc, 0.f);
    __syncthreads();
    if (i < 2) {
        float a = b2[i];
        for (int k = 0; k < 64; k++) a += hm[k] * W2[i * 64 + k];
        out[g * 2 + i] = a;
    }
}

extern "C" void kernel_launch(void* const* d_in, const int* in_sizes, int n_in,
                              void* d_out, int out_size, void* d_ws, size_t ws_size,
                              hipStream_t stream) {
    const float* x    = (const float*)d_in[0];
    const int*   ei   = (const int*)d_in[1];
    const int*   batch= (const int*)d_in[2];
    const float* lng  = (const float*)d_in[3];
    const float* lnb  = (const float*)d_in[4];
    const float* bn1g = (const float*)d_in[5];
    const float* bn1b = (const float*)d_in[6];
    const float* Wc   = (const float*)d_in[7];
    const float* bc   = (const float*)d_in[8];
    const float* bn2g = (const float*)d_in[9];
    const float* bn2b = (const float*)d_in[10];
    const float* Wp   = (const float*)d_in[11];
    const float* bp   = (const float*)d_in[12];
    const float* Wg   = (const float*)d_in[13];
    const float* atts = (const float*)d_in[14];
    const float* attd = (const float*)d_in[15];
    const float* bg   = (const float*)d_in[16];
    const float* bn3g = (const float*)d_in[17];
    const float* bn3b = (const float*)d_in[18];
    const float* W1   = (const float*)d_in[19];
    const float* b1   = (const float*)d_in[20];
    const float* W2   = (const float*)d_in[21];
    const float* b2   = (const float*)d_in[22];
    float* out = (float*)d_out;

    char* w8 = (char*)d_ws;
    float* bn1sum = (float*)(w8 + OFF_BN1SUM);
    float* bn1sq  = (float*)(w8 + OFF_BN1SQ);
    float* bn2sum = (float*)(w8 + OFF_BN2SUM);
    float* bn2sq  = (float*)(w8 + OFF_BN2SQ);
    float* bn3sum = (float*)(w8 + OFF_BN3SUM);
    float* bn3sq  = (float*)(w8 + OFF_BN3SQ);
    int*   count  = (int*)(w8 + OFF_COUNT);
    int*   cur    = (int*)(w8 + OFF_CUR);
    int*   offs   = (int*)(w8 + OFF_OFFS);
    int*   part   = (int*)(w8 + OFF_PART);
    float* Wc2    = (float*)(w8 + OFF_WC2);
    float* c2     = (float*)(w8 + OFF_C2);
    float* Wp2    = (float*)(w8 + OFF_WP2);
    float* cp     = (float*)(w8 + OFF_CP);
    float* Wgt    = (float*)(w8 + OFF_WGT);
    float* sc3    = (float*)(w8 + OFF_SC3);
    float* sh3    = (float*)(w8 + OFF_SH3);
    float* asrc   = (float*)(w8 + OFF_ASRC);
    float* adst   = (float*)(w8 + OFF_ADST);
    int*   srcs   = (int*)(w8 + OFF_SRCS);
    float* z      = (float*)(w8 + OFF_Z);
    float* h      = (float*)(w8 + OFF_H);
    float* z1     = (float*)(w8 + OFF_Z1);
    float* outp   = (float*)(w8 + OFF_OUTP);
    float* pooled = (float*)(w8 + OFF_POOL);

    hipMemsetAsync(d_ws, 0, ZERO_BYTES, stream);

    k_bn1_stats<<<256, 512, 0, stream>>>(x, bn1sum, bn1sq);
    k_fold1<<<1, 512, 0, stream>>>(bn1sum, bn1sq, bn1g, bn1b, Wc, bc, Wc2, c2);
    k_z<<<(N_ + 63) / 64, 512, 0, stream>>>(x, Wc2, c2, lng, lnb, z);
    k_bn2_stats<<<512, 256, 0, stream>>>(z, bn2sum, bn2sq);
    k_fold2<<<1, 64, 0, stream>>>(bn2sum, bn2sq, bn2g, bn2b, Wp, bp, Wp2, cp);
    k_wgt<<<64, 256, 0, stream>>>(Wg, Wgt);
    k_h1<<<196, 256, 0, stream>>>(z, Wp2, cp, z1);
    k_h2<<<(N_ + 127) / 128, 512, 0, stream>>>(z1, Wgt, atts, attd, h, asrc, adst);
    k_hist<<<E_ / 256, 256, 0, stream>>>(ei, count);
    const int SCANB = (N_ + 1023) / 1024;
    k_scan1<<<SCANB, 1024, 0, stream>>>(count, offs, part);
    k_scan2<<<1, 64, 0, stream>>>(part, SCANB);
    k_scan3<<<SCANB, 1024, 0, stream>>>(offs, part);
    k_scatter<<<E_ / 256, 256, 0, stream>>>(ei, offs, cur, srcs);
    k_agg<<<N_ / 4, 256, 0, stream>>>(count, offs, srcs, asrc, adst, h, bg, outp);
    k_bn3_stats<<<256, 256, 0, stream>>>(outp, bn3sum, bn3sq);
    k_fold3<<<1, 256, 0, stream>>>(bn3sum, bn3sq, bn3g, bn3b, sc3, sh3);
    k_pool<<<G_, 256, 0, stream>>>(outp, batch, sc3, sh3, pooled);
    k_mlp<<<G_, 64, 0, stream>>>(pooled, W1, b1, W2, b2, out);
}

// Round 3
// 582.647 us; speedup vs baseline: 2.2628x; 1.3231x over previous
//
#include <hip/hip_runtime.h>

static constexpr int N_   = 50000;
static constexpr int E_   = 800000;
static constexpr int G_   = 512;
static constexpr int IN_  = 544;
static constexpr float EPS_ = 1e-5f;

// ---------------- workspace byte offsets ----------------
static constexpr size_t OFF_BN1SUM = 0;          // 512 f
static constexpr size_t OFF_BN1SQ  = 2048;       // 512 f
static constexpr size_t OFF_BN2SUM = 4096;       // 48 f
static constexpr size_t OFF_BN2SQ  = 4288;       // 48 f
static constexpr size_t OFF_BN3SUM = 4480;       // 256 f
static constexpr size_t OFF_BN3SQ  = 5504;       // 256 f
static constexpr size_t OFF_COUNT  = 6528;       // N ints
static constexpr size_t OFF_CUR    = 206528;     // N ints
static constexpr size_t ZERO_BYTES = 406528;     // one memset covers all of the above
static constexpr size_t OFF_OFFS   = 406528;     // N ints
static constexpr size_t OFF_PART   = 606592;     // 64 ints
static constexpr size_t OFF_WC2    = 606848;     // 512*16 f
static constexpr size_t OFF_C2     = 639616;     // 16 f
static constexpr size_t OFF_WP2    = 639744;     // 48*64 f
static constexpr size_t OFF_CP     = 652032;     // 64 f
static constexpr size_t OFF_WGT    = 652288;     // 64*256 f
static constexpr size_t OFF_ASRC   = 719872;     // N*4 f
static constexpr size_t OFF_ADST   = 1519872;    // N*4 f
static constexpr size_t OFF_SRCS   = 2319872;    // E ints
static constexpr size_t OFF_Z      = 5519872;    // N*48 f (ends exactly at OFF_H)
static constexpr size_t OFF_H      = 15119872;   // N*64 ushort4 (bf16x4) = 25.6 MB
static constexpr size_t OFF_OUTP   = 66319872;   // N*256 f
static constexpr size_t OFF_POOL   = 117519872;  // G*256 f

#define DEV static __device__ __forceinline__

DEV float lrelu(float v) { return v > 0.f ? v : 0.2f * v; }
DEV unsigned short f2bf(float f) {
    unsigned u = __float_as_uint(f);
    return (unsigned short)((u + 0x7fffu + ((u >> 16) & 1u)) >> 16);
}
DEV float bf2f(unsigned short u) { return __uint_as_float(((unsigned)u) << 16); }

// ---------- 1. column sums/sumsq of x[:, :512] for bn1 (float4, LDS-reduced) ----------
__global__ __launch_bounds__(512) void k_bn1_stats(
        const float* __restrict__ x, float* __restrict__ sum, float* __restrict__ sq) {
    __shared__ float4 ta[512];
    __shared__ float4 tb[512];
    int t = threadIdx.x;                  // block 512 = 128 col-quads x 4 row-subs
    int cq = t & 127, rsub = t >> 7;
    int c4 = cq << 2;
    float4 a = make_float4(0.f, 0.f, 0.f, 0.f);
    float4 b = make_float4(0.f, 0.f, 0.f, 0.f);
    for (int r = blockIdx.x * 4 + rsub; r < N_; r += gridDim.x * 4) {
        float4 v = *(const float4*)(x + (size_t)r * IN_ + c4);
        a.x += v.x; a.y += v.y; a.z += v.z; a.w += v.w;
        b.x += v.x * v.x; b.y += v.y * v.y; b.z += v.z * v.z; b.w += v.w * v.w;
    }
    ta[t] = a; tb[t] = b;
    __syncthreads();
    if (t < 128) {
        float4 sa = ta[t], sb = tb[t];
#pragma unroll
        for (int r = 1; r < 4; r++) {
            float4 xa = ta[r * 128 + t], xb = tb[r * 128 + t];
            sa.x += xa.x; sa.y += xa.y; sa.z += xa.z; sa.w += xa.w;
            sb.x += xb.x; sb.y += xb.y; sb.z += xb.z; sb.w += xb.w;
        }
        int c = t << 2;
        atomicAdd(&sum[c + 0], sa.x); atomicAdd(&sum[c + 1], sa.y);
        atomicAdd(&sum[c + 2], sa.z); atomicAdd(&sum[c + 3], sa.w);
        atomicAdd(&sq[c + 0], sb.x);  atomicAdd(&sq[c + 1], sb.y);
        atomicAdd(&sq[c + 2], sb.z);  atomicAdd(&sq[c + 3], sb.w);
    }
}

// ---------- 2. fold bn1 into Wc ----------
__global__ void k_fold1(const float* __restrict__ sum, const float* __restrict__ sq,
                        const float* __restrict__ g, const float* __restrict__ b,
                        const float* __restrict__ Wc, const float* __restrict__ bc,
                        float* __restrict__ Wc2, float* __restrict__ c2) {
    __shared__ float t1[512];
    int j = threadIdx.x;                 // block 512
    float mu  = sum[j] / (float)N_;
    float var = sq[j] / (float)N_ - mu * mu;
    float s   = g[j] * rsqrtf(var + EPS_);
    t1[j] = b[j] - mu * s;
    for (int i = 0; i < 16; i++) Wc2[j * 16 + i] = Wc[i * 512 + j] * s;
    __syncthreads();
    if (j < 16) {
        float acc = bc[j];
        for (int k = 0; k < 512; k++) acc += t1[k] * Wc[j * 512 + k];
        c2[j] = acc;
    }
}

// ---------- 3. z = [x_cnn(16) | layernorm(f)(32)] + fused bn2 column stats ----------
__global__ __launch_bounds__(512) void k_z(
        const float* __restrict__ x, const float* __restrict__ Wc2g,
        const float* __restrict__ c2g, const float* __restrict__ lng,
        const float* __restrict__ lnb, float* __restrict__ z,
        float* __restrict__ bn2sum, float* __restrict__ bn2sq) {
    __shared__ float wc2[512 * 16];      // 32 KB
    __shared__ float c2s[16];
    __shared__ float bsum[48];
    __shared__ float bsq[48];
    int t = threadIdx.x;
    for (int q = t; q < 8192; q += 512) wc2[q] = Wc2g[q];
    if (t < 16) c2s[t] = c2g[t];
    if (t < 48) { bsum[t] = 0.f; bsq[t] = 0.f; }
    __syncthreads();
    int nd = t >> 3, i = t & 7;          // 8 threads per node
    int node = blockIdx.x * 64 + nd;     // grid 782
    bool valid = node < N_;
    int rn = valid ? node : N_ - 1;
    const float4* xr = (const float4*)(x + (size_t)rn * IN_);
    float acc0 = c2s[i], acc1 = c2s[i + 8];
    for (int u = 0; u < 128; u++) {
        float4 xv = xr[u];
        int j4 = u * 4;
        acc0 += xv.x * wc2[(j4 + 0) * 16 + i];
        acc0 += xv.y * wc2[(j4 + 1) * 16 + i];
        acc0 += xv.z * wc2[(j4 + 2) * 16 + i];
        acc0 += xv.w * wc2[(j4 + 3) * 16 + i];
        acc1 += xv.x * wc2[(j4 + 0) * 16 + i + 8];
        acc1 += xv.y * wc2[(j4 + 1) * 16 + i + 8];
        acc1 += xv.z * wc2[(j4 + 2) * 16 + i + 8];
        acc1 += xv.w * wc2[(j4 + 3) * 16 + i + 8];
    }
    // layernorm over last 32 cols
    float v[4]; float sm = 0.f, sqv = 0.f;
#pragma unroll
    for (int jj = 0; jj < 4; jj++) {
        v[jj] = x[(size_t)rn * IN_ + 512 + i + 8 * jj];
        sm += v[jj]; sqv += v[jj] * v[jj];
    }
    for (int m = 1; m < 8; m <<= 1) {
        sm  += __shfl_xor(sm, m);
        sqv += __shfl_xor(sqv, m);
    }
    float mu  = sm * (1.f / 32.f);
    float var = sqv * (1.f / 32.f) - mu * mu;
    float rs  = rsqrtf(var + EPS_);
    float outc[6];
    outc[0] = acc0; outc[1] = acc1;
#pragma unroll
    for (int jj = 0; jj < 4; jj++) {
        int c = i + 8 * jj;
        outc[2 + jj] = (v[jj] - mu) * rs * lng[c] + lnb[c];
    }
    if (valid) {
        z[node * 48 + i]     = acc0;
        z[node * 48 + i + 8] = acc1;
#pragma unroll
        for (int jj = 0; jj < 4; jj++) z[node * 48 + 16 + i + 8 * jj] = outc[2 + jj];
    }
    // bn2 partial sums: reduce across the 8 nodes of this wave (lanes i, i+8, ...)
    float s6[6], q6[6];
#pragma unroll
    for (int k = 0; k < 6; k++) {
        float vv = valid ? outc[k] : 0.f;
        s6[k] = vv; q6[k] = vv * vv;
    }
#pragma unroll
    for (int m = 8; m < 64; m <<= 1) {
#pragma unroll
        for (int k = 0; k < 6; k++) {
            s6[k] += __shfl_xor(s6[k], m);
            q6[k] += __shfl_xor(q6[k], m);
        }
    }
    if ((t & 63) < 8) {
        int cols[6] = { i, i + 8, 16 + i, 24 + i, 32 + i, 40 + i };
#pragma unroll
        for (int k = 0; k < 6; k++) {
            atomicAdd(&bsum[cols[k]], s6[k]);
            atomicAdd(&bsq[cols[k]],  q6[k]);
        }
    }
    __syncthreads();
    if (t < 48) {
        atomicAdd(&bn2sum[t], bsum[t]);
        atomicAdd(&bn2sq[t],  bsq[t]);
    }
}

// ---------- 5. fold bn2 into Wp ----------
__global__ void k_fold2(const float* __restrict__ sum, const float* __restrict__ sq,
                        const float* __restrict__ g, const float* __restrict__ b,
                        const float* __restrict__ Wp, const float* __restrict__ bp,
                        float* __restrict__ Wp2, float* __restrict__ cp) {
    __shared__ float t2[48];
    int i = threadIdx.x;                 // block 64
    if (i < 48) {
        float mu  = sum[i] / (float)N_;
        float var = sq[i] / (float)N_ - mu * mu;
        float s   = g[i] * rsqrtf(var + EPS_);
        t2[i] = b[i] - mu * s;
        for (int k = 0; k < 64; k++) Wp2[i * 64 + k] = Wp[k * 48 + i] * s;
    }
    __syncthreads();
    float acc = bp[i];
    for (int j = 0; j < 48; j++) acc += t2[j] * Wp[i * 48 + j];
    cp[i] = acc;
}

// ---------- 6. transpose Wg (256x64) -> Wgt (64x256) ----------
__global__ void k_wgt(const float* __restrict__ Wg, float* __restrict__ Wgt) {
    int idx = blockIdx.x * 256 + threadIdx.x;    // grid 64
    if (idx < 16384) {
        int c = idx >> 6, k = idx & 63;
        Wgt[k * 256 + c] = Wg[idx];
    }
}

// ---------- 7. z -> z1 (LDS only) -> h(bf16) + attention logits : 128 nodes/block ----------
__global__ __launch_bounds__(512) void k_h2(
        const float* __restrict__ z, const float* __restrict__ Wp2g,
        const float* __restrict__ cpg, const float* __restrict__ Wgtg,
        const float* __restrict__ att_s, const float* __restrict__ att_d,
        ushort4* __restrict__ hbf, float* __restrict__ asrc, float* __restrict__ adst) {
    __shared__ float4 wgh[32 * 64];      // 32 KB (z-tile staged here first)
    __shared__ float  z1t[128 * 64];     // 32 KB
    __shared__ float  wp2[48 * 64];      // 12 KB
    __shared__ float  cps[64];
    __shared__ float4 ats[64];
    __shared__ float4 atd[64];
    int t = threadIdx.x;                 // block 512, grid 391
    int base = blockIdx.x * 128;
    // stage z tile into wgh area (last block over-reads into h region slack; discarded)
    {
        const float4* z4 = (const float4*)(z + (size_t)base * 48);
        float4* zt4 = (float4*)wgh;
        for (int q = t; q < 1536; q += 512) zt4[q] = z4[q];
    }
    for (int q = t; q < 3072; q += 512) wp2[q] = Wp2g[q];
    if (t < 64) {
        cps[t] = cpg[t];
        ats[t] = ((const float4*)att_s)[t];
        atd[t] = ((const float4*)att_d)[t];
    }
    __syncthreads();
    int w = t >> 6, l = t & 63;          // l is invariant under t + p*512
    // phase 1: z1 = relu(z @ Wp2 + cp), Wp2 column held in registers
    {
        float wpr[48];
#pragma unroll
        for (int j = 0; j < 48; j++) wpr[j] = wp2[j * 64 + l];
        const float* zt = (const float*)wgh;
        for (int p = 0; p < 16; p++) {
            int nd = p * 8 + w;          // (p*512+t)>>6
            float acc = cps[l];
            const float* zr = zt + nd * 48;
#pragma unroll
            for (int j = 0; j < 48; j++) acc += zr[j] * wpr[j];
            z1t[nd * 64 + l] = fmaxf(acc, 0.f);
        }
    }
    // phase 2: h = z1 @ Wg.T (two k-halves; wgh overwrites the z-tile)
    const float4* wg4 = (const float4*)Wgtg;
    float4 acc[16];
#pragma unroll
    for (int nd = 0; nd < 16; nd++) acc[nd] = make_float4(0.f, 0.f, 0.f, 0.f);
    for (int half = 0; half < 2; half++) {
        __syncthreads();                 // z1t ready / previous wgh use done
        for (int q = t; q < 2048; q += 512) wgh[q] = wg4[half * 2048 + q];
        __syncthreads();
        int kbase = half * 32;
        for (int kk = 0; kk < 32; kk++) {
            float4 wv = wgh[kk * 64 + l];
            int k = kbase + kk;
#pragma unroll
            for (int nd = 0; nd < 16; nd++) {
                float zv = z1t[(w * 16 + nd) * 64 + k];
                acc[nd].x += zv * wv.x; acc[nd].y += zv * wv.y;
                acc[nd].z += zv * wv.z; acc[nd].w += zv * wv.w;
            }
        }
    }
    float4 as4 = ats[l], ad4 = atd[l];
#pragma unroll
    for (int nd = 0; nd < 16; nd++) {
        int node = base + w * 16 + nd;   // wave-uniform
        if (node < N_) {
            ushort4 hv;
            hv.x = f2bf(acc[nd].x); hv.y = f2bf(acc[nd].y);
            hv.z = f2bf(acc[nd].z); hv.w = f2bf(acc[nd].w);
            hbf[(size_t)node * 64 + l] = hv;
            float pa = acc[nd].x * as4.x + acc[nd].y * as4.y +
                       acc[nd].z * as4.z + acc[nd].w * as4.w;
            float pb = acc[nd].x * ad4.x + acc[nd].y * ad4.y +
                       acc[nd].z * ad4.z + acc[nd].w * ad4.w;
            for (int m = 1; m < 16; m <<= 1) {
                pa += __shfl_xor(pa, m);
                pb += __shfl_xor(pb, m);
            }
            if ((l & 15) == 0) {
                asrc[node * 4 + (l >> 4)] = pa;
                adst[node * 4 + (l >> 4)] = pb;
            }
        }
    }
}

// ---------- 8. edge histogram by dst ----------
__global__ void k_hist(const int* __restrict__ ei, int* __restrict__ count) {
    int k = blockIdx.x * 256 + threadIdx.x;      // grid 3125 -> exact
    atomicAdd(&count[ei[E_ + k]], 1);
}

// ---------- 9. three-phase exclusive scan ----------
__global__ void k_scan1(const int* __restrict__ count, int* __restrict__ offs,
                        int* __restrict__ part) {
    __shared__ int sd[1024];
    int t = threadIdx.x;
    int idx = blockIdx.x * 1024 + t;
    int v = (idx < N_) ? count[idx] : 0;
    sd[t] = v;
    for (int off = 1; off < 1024; off <<= 1) {
        __syncthreads();
        int tmp = (t >= off) ? sd[t - off] : 0;
        __syncthreads();
        sd[t] += tmp;
    }
    if (idx < N_) offs[idx] = sd[t] - v;
    if (t == 1023) part[blockIdx.x] = sd[1023];
}
__global__ void k_scan2(int* __restrict__ part, int nb) {
    if (threadIdx.x == 0) {
        int run = 0;
        for (int i = 0; i < nb; i++) { int tv = part[i]; part[i] = run; run += tv; }
    }
}
__global__ void k_scan3(int* __restrict__ offs, const int* __restrict__ part) {
    int idx = blockIdx.x * 1024 + threadIdx.x;
    if (idx < N_) offs[idx] += part[blockIdx.x];
}

// ---------- 10. scatter edges into dst-CSR ----------
__global__ void k_scatter(const int* __restrict__ ei, const int* __restrict__ offs,
                          int* __restrict__ cur, int* __restrict__ srcsort) {
    int k = blockIdx.x * 256 + threadIdx.x;
    int src = ei[k], dst = ei[E_ + k];
    int pos = offs[dst] + atomicAdd(&cur[dst], 1);
    srcsort[pos] = src;
}

// ---------- 11. per-dst softmax attention aggregation (wave per node, bf16 h) ----------
__global__ __launch_bounds__(256) void k_agg(
        const int* __restrict__ count, const int* __restrict__ offs,
        const int* __restrict__ srcsort, const float* __restrict__ asrc,
        const float* __restrict__ adst, const ushort4* __restrict__ hbf,
        const float* __restrict__ bg, float* __restrict__ outpre) {
    int w = threadIdx.x >> 6, l = threadIdx.x & 63;
    int dst = blockIdx.x * 4 + w;                 // grid 12500 -> exact
    const float4* asrc4 = (const float4*)asrc;
    float4* out4 = (float4*)outpre;
    float4 bgv = ((const float4*)bg)[l];
    int deg = count[dst];
    if (deg == 0) { out4[dst * 64 + l] = bgv; return; }
    int base = offs[dst];
    float4 ad = ((const float4*)adst)[dst];
    const float NEGINF = -__builtin_inff();
    int my_src = 0;
    float4 my_e = make_float4(NEGINF, NEGINF, NEGINF, NEGINF);
    if (l < deg) {
        my_src = srcsort[base + l];
        float4 a = asrc4[my_src];
        my_e = make_float4(lrelu(a.x + ad.x), lrelu(a.y + ad.y),
                           lrelu(a.z + ad.z), lrelu(a.w + ad.w));
    }
    float4 mx = my_e;
    for (int j = l + 64; j < deg; j += 64) {
        int s2 = srcsort[base + j];
        float4 a = asrc4[s2];
        mx.x = fmaxf(mx.x, lrelu(a.x + ad.x)); mx.y = fmaxf(mx.y, lrelu(a.y + ad.y));
        mx.z = fmaxf(mx.z, lrelu(a.z + ad.z)); mx.w = fmaxf(mx.w, lrelu(a.w + ad.w));
    }
    for (int m = 1; m < 64; m <<= 1) {
        mx.x = fmaxf(mx.x, __shfl_xor(mx.x, m));
        mx.y = fmaxf(mx.y, __shfl_xor(mx.y, m));
        mx.z = fmaxf(mx.z, __shfl_xor(mx.z, m));
        mx.w = fmaxf(mx.w, __shfl_xor(mx.w, m));
    }
    float4 sv = make_float4(0.f, 0.f, 0.f, 0.f);
    if (l < deg) {
        sv.x = __expf(my_e.x - mx.x); sv.y = __expf(my_e.y - mx.y);
        sv.z = __expf(my_e.z - mx.z); sv.w = __expf(my_e.w - mx.w);
    }
    for (int j = l + 64; j < deg; j += 64) {
        int s2 = srcsort[base + j];
        float4 a = asrc4[s2];
        sv.x += __expf(lrelu(a.x + ad.x) - mx.x);
        sv.y += __expf(lrelu(a.y + ad.y) - mx.y);
        sv.z += __expf(lrelu(a.z + ad.z) - mx.z);
        sv.w += __expf(lrelu(a.w + ad.w) - mx.w);
    }
    for (int m = 1; m < 64; m <<= 1) {
        sv.x += __shfl_xor(sv.x, m); sv.y += __shfl_xor(sv.y, m);
        sv.z += __shfl_xor(sv.z, m); sv.w += __shfl_xor(sv.w, m);
    }
    int hd = l >> 4;
    float mh  = hd == 0 ? mx.x : hd == 1 ? mx.y : hd == 2 ? mx.z : mx.w;
    float sh  = hd == 0 ? sv.x : hd == 1 ? sv.y : hd == 2 ? sv.z : sv.w;
    float adh = hd == 0 ? ad.x : hd == 1 ? ad.y : hd == 2 ? ad.z : ad.w;
    float inv = 1.f / fmaxf(sh, 1e-16f);
    float4 acc = make_float4(0.f, 0.f, 0.f, 0.f);
    for (int j = 0; j < deg; j++) {
        int src; float eh;
        if (j < 64) {
            src = __shfl(my_src, j);
            float ex_ = __shfl(my_e.x, j), ey_ = __shfl(my_e.y, j);
            float ez_ = __shfl(my_e.z, j), ew_ = __shfl(my_e.w, j);
            eh = hd == 0 ? ex_ : hd == 1 ? ey_ : hd == 2 ? ez_ : ew_;
        } else {
            src = srcsort[base + j];
            float4 a = asrc4[src];
            float ah = hd == 0 ? a.x : hd == 1 ? a.y : hd == 2 ? a.z : a.w;
            eh = lrelu(ah + adh);
        }
        float wgt = __expf(eh - mh) * inv;
        ushort4 hv = hbf[(size_t)src * 64 + l];
        acc.x += wgt * bf2f(hv.x); acc.y += wgt * bf2f(hv.y);
        acc.z += wgt * bf2f(hv.z); acc.w += wgt * bf2f(hv.w);
    }
    out4[dst * 64 + l] = make_float4(acc.x + bgv.x, acc.y + bgv.y,
                                     acc.z + bgv.z, acc.w + bgv.w);
}

// ---------- 12. column stats of outpre (256 cols, float4) ----------
__global__ __launch_bounds__(256) void k_bn3_stats(
        const float* __restrict__ op, float* __restrict__ sum, float* __restrict__ sq) {
    __shared__ float4 ta[256];
    __shared__ float4 tb[256];
    int t = threadIdx.x;                 // 64 col-quads x 4 row-subs
    int cq = t & 63, rsub = t >> 6;
    int c4 = cq << 2;
    float4 a = make_float4(0.f, 0.f, 0.f, 0.f);
    float4 b = make_float4(0.f, 0.f, 0.f, 0.f);
    for (int r = blockIdx.x * 4 + rsub; r < N_; r += gridDim.x * 4) {
        float4 v = *(const float4*)(op + (size_t)r * 256 + c4);
        a.x += v.x; a.y += v.y; a.z += v.z; a.w += v.w;
        b.x += v.x * v.x; b.y += v.y * v.y; b.z += v.z * v.z; b.w += v.w * v.w;
    }
    ta[t] = a; tb[t] = b;
    __syncthreads();
    if (t < 64) {
        float4 sa = ta[t], sb = tb[t];
#pragma unroll
        for (int r = 1; r < 4; r++) {
            float4 xa = ta[r * 64 + t], xb = tb[r * 64 + t];
            sa.x += xa.x; sa.y += xa.y; sa.z += xa.z; sa.w += xa.w;
            sb.x += xb.x; sb.y += xb.y; sb.z += xb.z; sb.w += xb.w;
        }
        int c = t << 2;
        atomicAdd(&sum[c + 0], sa.x); atomicAdd(&sum[c + 1], sa.y);
        atomicAdd(&sum[c + 2], sa.z); atomicAdd(&sum[c + 3], sa.w);
        atomicAdd(&sq[c + 0], sb.x);  atomicAdd(&sq[c + 1], sb.y);
        atomicAdd(&sq[c + 2], sb.z);  atomicAdd(&sq[c + 3], sb.w);
    }
}

// ---------- 13. graph mean-pool of elu(bn3(outpre)); bn3 fold inlined ----------
__global__ __launch_bounds__(256) void k_pool(
        const float* __restrict__ op, const int* __restrict__ batch,
        const float* __restrict__ bn3sum, const float* __restrict__ bn3sq,
        const float* __restrict__ bn3g, const float* __restrict__ bn3b,
        float* __restrict__ pooled) {
    __shared__ float4 tile[256];
    int g = blockIdx.x;                  // grid 512
    int t = threadIdx.x;
    int cq = t & 63, rsub = t >> 6;
    int c4 = cq << 2;
    int lo = 0, hi = N_;
    while (lo < hi) { int mid = (lo + hi) >> 1; if (batch[mid] < g) lo = mid + 1; else hi = mid; }
    int start = lo;
    hi = N_;
    while (lo < hi) { int mid = (lo + hi) >> 1; if (batch[mid] < g + 1) lo = mid + 1; else hi = mid; }
    int end = lo;
    float scv[4], shv[4];
#pragma unroll
    for (int k = 0; k < 4; k++) {
        int c = c4 + k;
        float mu  = bn3sum[c] / (float)N_;
        float var = bn3sq[c] / (float)N_ - mu * mu;
        float s   = bn3g[c] * rsqrtf(var + EPS_);
        scv[k] = s; shv[k] = bn3b[c] - mu * s;
    }
    float4 acc = make_float4(0.f, 0.f, 0.f, 0.f);
    for (int n = start + rsub; n < end; n += 4) {
        float4 v = *(const float4*)(op + (size_t)n * 256 + c4);
        float e0 = v.x * scv[0] + shv[0], e1 = v.y * scv[1] + shv[1];
        float e2 = v.z * scv[2] + shv[2], e3 = v.w * scv[3] + shv[3];
        acc.x += (e0 > 0.f) ? e0 : expm1f(e0);
        acc.y += (e1 > 0.f) ? e1 : expm1f(e1);
        acc.z += (e2 > 0.f) ? e2 : expm1f(e2);
        acc.w += (e3 > 0.f) ? e3 : expm1f(e3);
    }
    tile[t] = acc;
    __syncthreads();
    if (t < 64) {
        float4 s = tile[t];
#pragma unroll
        for (int r = 1; r < 4; r++) {
            float4 xv = tile[r * 64 + t];
            s.x += xv.x; s.y += xv.y; s.z += xv.z; s.w += xv.w;
        }
        float cn = fmaxf((float)(end - start), 1.f);
        float icn = 1.f / cn;
        ((float4*)(pooled + (size_t)g * 256))[t] =
            make_float4(s.x * icn, s.y * icn, s.z * icn, s.w * icn);
    }
}

// ---------- 14. final MLP ----------
__global__ void k_mlp(const float* __restrict__ pooled, const float* __restrict__ W1,
                      const float* __restrict__ b1, const float* __restrict__ W2,
                      const float* __restrict__ b2, float* __restrict__ out) {
    __shared__ float pl[256];
    __shared__ float hm[64];
    int g = blockIdx.x;                  // grid 512, block 64
    int i = threadIdx.x;
    for (int q = i; q < 256; q += 64) pl[q] = pooled[g * 256 + q];
    __syncthreads();
    float acc = b1[i];
    for (int c = 0; c < 256; c++) acc += pl[c] * W1[i * 256 + c];
    hm[i] = fmaxf(acc, 0.f);
    __syncthreads();
    if (i < 2) {
        float a = b2[i];
        for (int k = 0; k < 64; k++) a += hm[k] * W2[i * 64 + k];
        out[g * 2 + i] = a;
    }
}

extern "C" void kernel_launch(void* const* d_in, const int* in_sizes, int n_in,
                              void* d_out, int out_size, void* d_ws, size_t ws_size,
                              hipStream_t stream) {
    const float* x    = (const float*)d_in[0];
    const int*   ei   = (const int*)d_in[1];
    const int*   batch= (const int*)d_in[2];
    const float* lng  = (const float*)d_in[3];
    const float* lnb  = (const float*)d_in[4];
    const float* bn1g = (const float*)d_in[5];
    const float* bn1b = (const float*)d_in[6];
    const float* Wc   = (const float*)d_in[7];
    const float* bc   = (const float*)d_in[8];
    const float* bn2g = (const float*)d_in[9];
    const float* bn2b = (const float*)d_in[10];
    const float* Wp   = (const float*)d_in[11];
    const float* bp   = (const float*)d_in[12];
    const float* Wg   = (const float*)d_in[13];
    const float* atts = (const float*)d_in[14];
    const float* attd = (const float*)d_in[15];
    const float* bg   = (const float*)d_in[16];
    const float* bn3g = (const float*)d_in[17];
    const float* bn3b = (const float*)d_in[18];
    const float* W1   = (const float*)d_in[19];
    const float* b1   = (const float*)d_in[20];
    const float* W2   = (const float*)d_in[21];
    const float* b2   = (const float*)d_in[22];
    float* out = (float*)d_out;

    char* w8 = (char*)d_ws;
    float* bn1sum = (float*)(w8 + OFF_BN1SUM);
    float* bn1sq  = (float*)(w8 + OFF_BN1SQ);
    float* bn2sum = (float*)(w8 + OFF_BN2SUM);
    float* bn2sq  = (float*)(w8 + OFF_BN2SQ);
    float* bn3sum = (float*)(w8 + OFF_BN3SUM);
    float* bn3sq  = (float*)(w8 + OFF_BN3SQ);
    int*   count  = (int*)(w8 + OFF_COUNT);
    int*   cur    = (int*)(w8 + OFF_CUR);
    int*   offs   = (int*)(w8 + OFF_OFFS);
    int*   part   = (int*)(w8 + OFF_PART);
    float* Wc2    = (float*)(w8 + OFF_WC2);
    float* c2     = (float*)(w8 + OFF_C2);
    float* Wp2    = (float*)(w8 + OFF_WP2);
    float* cp     = (float*)(w8 + OFF_CP);
    float* Wgt    = (float*)(w8 + OFF_WGT);
    float* asrc   = (float*)(w8 + OFF_ASRC);
    float* adst   = (float*)(w8 + OFF_ADST);
    int*   srcs   = (int*)(w8 + OFF_SRCS);
    float* z      = (float*)(w8 + OFF_Z);
    ushort4* hbf  = (ushort4*)(w8 + OFF_H);
    float* outp   = (float*)(w8 + OFF_OUTP);
    float* pooled = (float*)(w8 + OFF_POOL);

    hipMemsetAsync(d_ws, 0, ZERO_BYTES, stream);

    k_bn1_stats<<<256, 512, 0, stream>>>(x, bn1sum, bn1sq);
    k_fold1<<<1, 512, 0, stream>>>(bn1sum, bn1sq, bn1g, bn1b, Wc, bc, Wc2, c2);
    k_z<<<(N_ + 63) / 64, 512, 0, stream>>>(x, Wc2, c2, lng, lnb, z, bn2sum, bn2sq);
    k_fold2<<<1, 64, 0, stream>>>(bn2sum, bn2sq, bn2g, bn2b, Wp, bp, Wp2, cp);
    k_wgt<<<64, 256, 0, stream>>>(Wg, Wgt);
    k_h2<<<(N_ + 127) / 128, 512, 0, stream>>>(z, Wp2, cp, Wgt, atts, attd, hbf, asrc, adst);
    k_hist<<<E_ / 256, 256, 0, stream>>>(ei, count);
    const int SCANB = (N_ + 1023) / 1024;
    k_scan1<<<SCANB, 1024, 0, stream>>>(count, offs, part);
    k_scan2<<<1, 64, 0, stream>>>(part, SCANB);
    k_scan3<<<SCANB, 1024, 0, stream>>>(offs, part);
    k_scatter<<<E_ / 256, 256, 0, stream>>>(ei, offs, cur, srcs);
    k_agg<<<N_ / 4, 256, 0, stream>>>(count, offs, srcs, asrc, adst, hbf, bg, outp);
    k_bn3_stats<<<256, 256, 0, stream>>>(outp, bn3sum, bn3sq);
    k_pool<<<G_, 256, 0, stream>>>(outp, batch, bn3sum, bn3sq, bn3g, bn3b, pooled);
    k_mlp<<<G_, 64, 0, stream>>>(pooled, W1, b1, W2, b2, out);
}

// Round 4
// 554.963 us; speedup vs baseline: 2.3757x; 1.0499x over previous
//
#include <hip/hip_runtime.h>

static constexpr int N_   = 50000;
static constexpr int E_   = 800000;
static constexpr int G_   = 512;
static constexpr int IN_  = 544;
static constexpr float EPS_ = 1e-5f;

// ---------------- workspace byte offsets ----------------
static constexpr size_t OFF_BN1SUM = 0;          // 512 f
static constexpr size_t OFF_BN1SQ  = 2048;       // 512 f
static constexpr size_t OFF_BN2SUM = 4096;       // 48 f
static constexpr size_t OFF_BN2SQ  = 4288;       // 48 f
static constexpr size_t OFF_BN3SUM = 4480;       // 256 f
static constexpr size_t OFF_BN3SQ  = 5504;       // 256 f
static constexpr size_t OFF_COUNT  = 6528;       // N ints
static constexpr size_t OFF_CUR    = 206528;     // N ints
static constexpr size_t ZERO_BYTES = 406528;     // one memset covers all of the above
static constexpr size_t OFF_OFFS   = 406528;     // N ints
static constexpr size_t OFF_PART   = 606592;     // 64 ints
static constexpr size_t OFF_WC2    = 606848;     // 16*512 f (TRANSPOSED: [16][512])
static constexpr size_t OFF_C2     = 639616;     // 16 f
static constexpr size_t OFF_WP2    = 639744;     // 48*64 f
static constexpr size_t OFF_CP     = 652032;     // 64 f
static constexpr size_t OFF_WGT    = 652288;     // 64*256 f
static constexpr size_t OFF_ASRC   = 719872;     // N*4 f
static constexpr size_t OFF_ADST   = 1519872;    // N*4 f
static constexpr size_t OFF_SRCS   = 2319872;    // E ints
static constexpr size_t OFF_Z      = 5519872;    // N*48 f
static constexpr size_t OFF_H      = 15119872;   // N*64 ushort4 (bf16x4) = 25.6 MB
static constexpr size_t OFF_OUTP   = 66319872;   // N*256 f
static constexpr size_t OFF_POOL   = 117519872;  // (reserved)

#define DEV static __device__ __forceinline__

DEV float lrelu(float v) { return v > 0.f ? v : 0.2f * v; }
DEV unsigned short f2bf(float f) {
    unsigned u = __float_as_uint(f);
    return (unsigned short)((u + 0x7fffu + ((u >> 16) & 1u)) >> 16);
}

// ---------- 1. bn1 column stats (blocks 0..255) + edge histogram (rest) ----------
__global__ __launch_bounds__(512) void k_bn1_hist(
        const float* __restrict__ x, float* __restrict__ sum, float* __restrict__ sq,
        const int* __restrict__ ei, int* __restrict__ count) {
    __shared__ float4 ta[512];
    __shared__ float4 tb[512];
    int bid = blockIdx.x;
    int t = threadIdx.x;
    if (bid >= 256) {
        int k = (bid - 256) * 512 + t;
        if (k < E_) atomicAdd(&count[ei[E_ + k]], 1);
        return;
    }
    int cq = t & 127, rsub = t >> 7;
    int c4 = cq << 2;
    float4 a = make_float4(0.f, 0.f, 0.f, 0.f);
    float4 b = make_float4(0.f, 0.f, 0.f, 0.f);
    for (int r = bid * 4 + rsub; r < N_; r += 256 * 4) {
        float4 v = *(const float4*)(x + (size_t)r * IN_ + c4);
        a.x += v.x; a.y += v.y; a.z += v.z; a.w += v.w;
        b.x += v.x * v.x; b.y += v.y * v.y; b.z += v.z * v.z; b.w += v.w * v.w;
    }
    ta[t] = a; tb[t] = b;
    __syncthreads();
    if (t < 128) {
        float4 sa = ta[t], sb = tb[t];
#pragma unroll
        for (int r = 1; r < 4; r++) {
            float4 xa = ta[r * 128 + t], xb = tb[r * 128 + t];
            sa.x += xa.x; sa.y += xa.y; sa.z += xa.z; sa.w += xa.w;
            sb.x += xb.x; sb.y += xb.y; sb.z += xb.z; sb.w += xb.w;
        }
        int c = t << 2;
        atomicAdd(&sum[c + 0], sa.x); atomicAdd(&sum[c + 1], sa.y);
        atomicAdd(&sum[c + 2], sa.z); atomicAdd(&sum[c + 3], sa.w);
        atomicAdd(&sq[c + 0], sb.x);  atomicAdd(&sq[c + 1], sb.y);
        atomicAdd(&sq[c + 2], sb.z);  atomicAdd(&sq[c + 3], sb.w);
    }
}

// ---------- 2. fold bn1 into Wc (transposed out) + parallel c2 ----------
__global__ __launch_bounds__(512) void k_fold1(
        const float* __restrict__ sum, const float* __restrict__ sq,
        const float* __restrict__ g, const float* __restrict__ b,
        const float* __restrict__ Wc, const float* __restrict__ bc,
        float* __restrict__ Wc2t, float* __restrict__ c2) {
    __shared__ float c2s[16];
    int j = threadIdx.x;                 // block 512
    if (j < 16) c2s[j] = 0.f;
    float mu  = sum[j] / (float)N_;
    float var = sq[j] / (float)N_ - mu * mu;
    float s   = g[j] * rsqrtf(var + EPS_);
    float tj  = b[j] - mu * s;
    __syncthreads();
    for (int i = 0; i < 16; i++) {
        float wv = Wc[i * 512 + j];
        Wc2t[i * 512 + j] = wv * s;      // coalesced
        float p = tj * wv;
        for (int m = 1; m < 64; m <<= 1) p += __shfl_xor(p, m);
        if ((j & 63) == 0) atomicAdd(&c2s[i], p);
    }
    __syncthreads();
    if (j < 16) c2[j] = c2s[j] + bc[j];
}

// ---------- 3. z = [x_cnn(16) | layernorm(f)(32)] + fused bn2 column stats ----------
static constexpr int WSTRIDE = 516;      // 512+4: bank-shift 4/row -> conflict-free
__global__ __launch_bounds__(512) void k_z(
        const float* __restrict__ x, const float* __restrict__ Wc2tg,
        const float* __restrict__ c2g, const float* __restrict__ lng,
        const float* __restrict__ lnb, float* __restrict__ z,
        float* __restrict__ bn2sum, float* __restrict__ bn2sq) {
    __shared__ float wc2[16 * WSTRIDE];  // 33 KB
    __shared__ float c2s[16];
    __shared__ float bsum[48];
    __shared__ float bsq[48];
    int t = threadIdx.x;
    for (int q = t; q < 8192; q += 512) {
        int row = q >> 9, col = q & 511;
        wc2[row * WSTRIDE + col] = Wc2tg[q];
    }
    if (t < 16) c2s[t] = c2g[t];
    if (t < 48) { bsum[t] = 0.f; bsq[t] = 0.f; }
    __syncthreads();
    int nd = t >> 3, i = t & 7;          // 8 threads per node
    int node = blockIdx.x * 64 + nd;     // grid 782
    bool valid = node < N_;
    int rn = valid ? node : N_ - 1;
    const float4* xr = (const float4*)(x + (size_t)rn * IN_);
    const float4* w0 = (const float4*)(wc2 + i * WSTRIDE);
    const float4* w1 = (const float4*)(wc2 + (i + 8) * WSTRIDE);
    float acc0 = c2s[i], acc1 = c2s[i + 8];
    for (int u = 0; u < 128; u++) {
        float4 xv = xr[u];
        float4 a4 = w0[u];
        float4 b4 = w1[u];
        acc0 += xv.x * a4.x + xv.y * a4.y + xv.z * a4.z + xv.w * a4.w;
        acc1 += xv.x * b4.x + xv.y * b4.y + xv.z * b4.z + xv.w * b4.w;
    }
    // layernorm over last 32 cols
    float v[4]; float sm = 0.f, sqv = 0.f;
#pragma unroll
    for (int jj = 0; jj < 4; jj++) {
        v[jj] = x[(size_t)rn * IN_ + 512 + i + 8 * jj];
        sm += v[jj]; sqv += v[jj] * v[jj];
    }
    for (int m = 1; m < 8; m <<= 1) {
        sm  += __shfl_xor(sm, m);
        sqv += __shfl_xor(sqv, m);
    }
    float mu  = sm * (1.f / 32.f);
    float var = sqv * (1.f / 32.f) - mu * mu;
    float rs  = rsqrtf(var + EPS_);
    float outc[6];
    outc[0] = acc0; outc[1] = acc1;
#pragma unroll
    for (int jj = 0; jj < 4; jj++) {
        int c = i + 8 * jj;
        outc[2 + jj] = (v[jj] - mu) * rs * lng[c] + lnb[c];
    }
    if (valid) {
        z[node * 48 + i]     = acc0;
        z[node * 48 + i + 8] = acc1;
#pragma unroll
        for (int jj = 0; jj < 4; jj++) z[node * 48 + 16 + i + 8 * jj] = outc[2 + jj];
    }
    float s6[6], q6[6];
#pragma unroll
    for (int k = 0; k < 6; k++) {
        float vv = valid ? outc[k] : 0.f;
        s6[k] = vv; q6[k] = vv * vv;
    }
#pragma unroll
    for (int m = 8; m < 64; m <<= 1) {
#pragma unroll
        for (int k = 0; k < 6; k++) {
            s6[k] += __shfl_xor(s6[k], m);
            q6[k] += __shfl_xor(q6[k], m);
        }
    }
    if ((t & 63) < 8) {
        int cols[6] = { i, i + 8, 16 + i, 24 + i, 32 + i, 40 + i };
#pragma unroll
        for (int k = 0; k < 6; k++) {
            atomicAdd(&bsum[cols[k]], s6[k]);
            atomicAdd(&bsq[cols[k]],  q6[k]);
        }
    }
    __syncthreads();
    if (t < 48) {
        atomicAdd(&bn2sum[t], bsum[t]);
        atomicAdd(&bn2sq[t],  bsq[t]);
    }
}

// ---------- 4. fold bn2 into Wp (block 0) + Wg transpose (blocks 1..64) ----------
__global__ __launch_bounds__(256) void k_fold2_wgt(
        const float* __restrict__ sum, const float* __restrict__ sq,
        const float* __restrict__ g, const float* __restrict__ b,
        const float* __restrict__ Wp, const float* __restrict__ bp,
        float* __restrict__ Wp2, float* __restrict__ cp,
        const float* __restrict__ Wg, float* __restrict__ Wgt) {
    __shared__ float t2[48];
    int t = threadIdx.x;
    if (blockIdx.x > 0) {
        int idx = (blockIdx.x - 1) * 256 + t;
        int c = idx >> 6, k = idx & 63;
        Wgt[k * 256 + c] = Wg[idx];
        return;
    }
    if (t < 48) {
        float mu  = sum[t] / (float)N_;
        float var = sq[t] / (float)N_ - mu * mu;
        float s   = g[t] * rsqrtf(var + EPS_);
        t2[t] = b[t] - mu * s;
        for (int k = 0; k < 64; k++) Wp2[t * 64 + k] = Wp[k * 48 + t] * s;
    }
    __syncthreads();
    if (t < 64) {
        float acc = bp[t];
        for (int j = 0; j < 48; j++) acc += t2[j] * Wp[t * 48 + j];
        cp[t] = acc;
    }
}

// ---------- 5. scan phase 1 ----------
__global__ void k_scan1(const int* __restrict__ count, int* __restrict__ offs,
                        int* __restrict__ part) {
    __shared__ int sd[1024];
    int t = threadIdx.x;
    int idx = blockIdx.x * 1024 + t;
    int v = (idx < N_) ? count[idx] : 0;
    sd[t] = v;
    for (int off = 1; off < 1024; off <<= 1) {
        __syncthreads();
        int tmp = (t >= off) ? sd[t - off] : 0;
        __syncthreads();
        sd[t] += tmp;
    }
    if (idx < N_) offs[idx] = sd[t] - v;
    if (t == 1023) part[blockIdx.x] = sd[1023];
}
// ---------- 6. scan phases 2+3: per-block prefix of parts, wave-reduced ----------
__global__ void k_scan23(int* __restrict__ offs, const int* __restrict__ part) {
    __shared__ int bs;
    int t = threadIdx.x, b = blockIdx.x;
    if (t < 64) {
        int v = (t < b) ? part[t] : 0;   // b <= 48 < 64
        for (int m = 1; m < 64; m <<= 1) v += __shfl_xor(v, m);
        if (t == 0) bs = v;
    }
    __syncthreads();
    int idx = b * 1024 + t;
    if (idx < N_) offs[idx] += bs;
}

// ---------- 7. scatter edges into dst-CSR ----------
__global__ void k_scatter(const int* __restrict__ ei, const int* __restrict__ offs,
                          int* __restrict__ cur, int* __restrict__ srcsort) {
    int k = blockIdx.x * 256 + threadIdx.x;
    int src = ei[k], dst = ei[E_ + k];
    int pos = offs[dst] + atomicAdd(&cur[dst], 1);
    srcsort[pos] = src;
}

// ---------- 8. z -> z1 (LDS only) -> h(bf16) + attention logits : 128 nodes/block ----------
__global__ __launch_bounds__(512) void k_h2(
        const float* __restrict__ z, const float* __restrict__ Wp2g,
        const float* __restrict__ cpg, const float* __restrict__ Wgtg,
        const float* __restrict__ att_s, const float* __restrict__ att_d,
        ushort4* __restrict__ hbf, float* __restrict__ asrc, float* __restrict__ adst) {
    __shared__ float4 wgh[32 * 64];      // 32 KB (z-tile staged here first)
    __shared__ float  z1t[128 * 64];     // 32 KB
    __shared__ float  wp2[48 * 64];      // 12 KB
    __shared__ float  cps[64];
    __shared__ float4 ats[64];
    __shared__ float4 atd[64];
    int t = threadIdx.x;                 // block 512, grid 391
    int base = blockIdx.x * 128;
    {
        const float4* z4 = (const float4*)(z + (size_t)base * 48);
        float4* zt4 = (float4*)wgh;
        for (int q = t; q < 1536; q += 512) zt4[q] = z4[q];
    }
    for (int q = t; q < 3072; q += 512) wp2[q] = Wp2g[q];
    if (t < 64) {
        cps[t] = cpg[t];
        ats[t] = ((const float4*)att_s)[t];
        atd[t] = ((const float4*)att_d)[t];
    }
    __syncthreads();
    int w = t >> 6, l = t & 63;
    {
        float wpr[48];
#pragma unroll
        for (int j = 0; j < 48; j++) wpr[j] = wp2[j * 64 + l];
        const float* zt = (const float*)wgh;
        for (int p = 0; p < 16; p++) {
            int nd = p * 8 + w;
            float acc = cps[l];
            const float* zr = zt + nd * 48;
#pragma unroll
            for (int j = 0; j < 48; j++) acc += zr[j] * wpr[j];
            z1t[nd * 64 + l] = fmaxf(acc, 0.f);
        }
    }
    const float4* wg4 = (const float4*)Wgtg;
    float4 acc[16];
#pragma unroll
    for (int nd = 0; nd < 16; nd++) acc[nd] = make_float4(0.f, 0.f, 0.f, 0.f);
    for (int half = 0; half < 2; half++) {
        __syncthreads();
        for (int q = t; q < 2048; q += 512) wgh[q] = wg4[half * 2048 + q];
        __syncthreads();
        int kbase = half * 32;
        for (int kk = 0; kk < 32; kk++) {
            float4 wv = wgh[kk * 64 + l];
            int k = kbase + kk;
#pragma unroll
            for (int nd = 0; nd < 16; nd++) {
                float zv = z1t[(w * 16 + nd) * 64 + k];
                acc[nd].x += zv * wv.x; acc[nd].y += zv * wv.y;
                acc[nd].z += zv * wv.z; acc[nd].w += zv * wv.w;
            }
        }
    }
    float4 as4 = ats[l], ad4 = atd[l];
#pragma unroll
    for (int nd = 0; nd < 16; nd++) {
        int node = base + w * 16 + nd;   // wave-uniform
        if (node < N_) {
            ushort4 hv;
            hv.x = f2bf(acc[nd].x); hv.y = f2bf(acc[nd].y);
            hv.z = f2bf(acc[nd].z); hv.w = f2bf(acc[nd].w);
            hbf[(size_t)node * 64 + l] = hv;
            float pa = acc[nd].x * as4.x + acc[nd].y * as4.y +
                       acc[nd].z * as4.z + acc[nd].w * as4.w;
            float pb = acc[nd].x * ad4.x + acc[nd].y * ad4.y +
                       acc[nd].z * ad4.z + acc[nd].w * ad4.w;
            for (int m = 1; m < 16; m <<= 1) {
                pa += __shfl_xor(pa, m);
                pb += __shfl_xor(pb, m);
            }
            if ((l & 15) == 0) {
                asrc[node * 4 + (l >> 4)] = pa;
                adst[node * 4 + (l >> 4)] = pb;
            }
        }
    }
}

// ---------- 9. per-dst softmax aggregation: LDS-cached srcs + exp-weights ----------
__global__ __launch_bounds__(256) void k_agg(
        const int* __restrict__ count, const int* __restrict__ offs,
        const int* __restrict__ srcsort, const float* __restrict__ asrc,
        const float* __restrict__ adst, const ushort4* __restrict__ hbf,
        const float* __restrict__ bg, float* __restrict__ outpre) {
    __shared__ int   s_src[4][128];      // 2 KB
    __shared__ float s_wf[4][512];       // 8 KB: per edge, 4 head exp-weights
    int w = threadIdx.x >> 6, l = threadIdx.x & 63;
    int dst = blockIdx.x * 4 + w;        // grid 12500 -> exact
    const float4* asrc4 = (const float4*)asrc;
    float4* out4 = (float4*)outpre;
    float4 bgv = ((const float4*)bg)[l];
    int deg = count[dst];
    if (deg == 0) { out4[dst * 64 + l] = bgv; return; }
    int base = offs[dst];
    float4 ad = ((const float4*)adst)[dst];
    const float NEGINF = -__builtin_inff();
    // pass A: strips j=l, j=l+64 in registers; cache srcs in LDS
    float4 e0 = make_float4(NEGINF, NEGINF, NEGINF, NEGINF);
    float4 e1 = make_float4(NEGINF, NEGINF, NEGINF, NEGINF);
    if (l < deg) {
        int s0 = srcsort[base + l];
        s_src[w][l] = s0;
        float4 a = asrc4[s0];
        e0 = make_float4(lrelu(a.x + ad.x), lrelu(a.y + ad.y),
                         lrelu(a.z + ad.z), lrelu(a.w + ad.w));
    }
    if (l + 64 < deg) {
        int s1 = srcsort[base + l + 64];
        s_src[w][l + 64] = s1;
        float4 a = asrc4[s1];
        e1 = make_float4(lrelu(a.x + ad.x), lrelu(a.y + ad.y),
                         lrelu(a.z + ad.z), lrelu(a.w + ad.w));
    }
    float4 mx = make_float4(fmaxf(e0.x, e1.x), fmaxf(e0.y, e1.y),
                            fmaxf(e0.z, e1.z), fmaxf(e0.w, e1.w));
    for (int j = l + 128; j < deg; j += 64) {     // rare overflow path
        int s2 = srcsort[base + j];
        float4 a = asrc4[s2];
        mx.x = fmaxf(mx.x, lrelu(a.x + ad.x)); mx.y = fmaxf(mx.y, lrelu(a.y + ad.y));
        mx.z = fmaxf(mx.z, lrelu(a.z + ad.z)); mx.w = fmaxf(mx.w, lrelu(a.w + ad.w));
    }
    for (int m = 1; m < 64; m <<= 1) {
        mx.x = fmaxf(mx.x, __shfl_xor(mx.x, m));
        mx.y = fmaxf(mx.y, __shfl_xor(mx.y, m));
        mx.z = fmaxf(mx.z, __shfl_xor(mx.z, m));
        mx.w = fmaxf(mx.w, __shfl_xor(mx.w, m));
    }
    // pass B: exp, cache to LDS, reduce sum
    float4 sv = make_float4(0.f, 0.f, 0.f, 0.f);
    if (l < deg) {
        float4 ex = make_float4(__expf(e0.x - mx.x), __expf(e0.y - mx.y),
                                __expf(e0.z - mx.z), __expf(e0.w - mx.w));
        *(float4*)&s_wf[w][l * 4] = ex;
        sv.x += ex.x; sv.y += ex.y; sv.z += ex.z; sv.w += ex.w;
    }
    if (l + 64 < deg) {
        float4 ex = make_float4(__expf(e1.x - mx.x), __expf(e1.y - mx.y),
                                __expf(e1.z - mx.z), __expf(e1.w - mx.w));
        *(float4*)&s_wf[w][(l + 64) * 4] = ex;
        sv.x += ex.x; sv.y += ex.y; sv.z += ex.z; sv.w += ex.w;
    }
    for (int j = l + 128; j < deg; j += 64) {     // rare
        int s2 = srcsort[base + j];
        float4 a = asrc4[s2];
        sv.x += __expf(lrelu(a.x + ad.x) - mx.x);
        sv.y += __expf(lrelu(a.y + ad.y) - mx.y);
        sv.z += __expf(lrelu(a.z + ad.z) - mx.z);
        sv.w += __expf(lrelu(a.w + ad.w) - mx.w);
    }
    for (int m = 1; m < 64; m <<= 1) {
        sv.x += __shfl_xor(sv.x, m); sv.y += __shfl_xor(sv.y, m);
        sv.z += __shfl_xor(sv.z, m); sv.w += __shfl_xor(sv.w, m);
    }
    int hd = l >> 4;
    float mh  = hd == 0 ? mx.x : hd == 1 ? mx.y : hd == 2 ? mx.z : mx.w;
    float sh  = hd == 0 ? sv.x : hd == 1 ? sv.y : hd == 2 ? sv.z : sv.w;
    float adh = hd == 0 ? ad.x : hd == 1 ? ad.y : hd == 2 ? ad.z : ad.w;
    float inv = 1.f / fmaxf(sh, 1e-16f);
    // pass C: weighted gather-accumulate
    float4 accv = make_float4(0.f, 0.f, 0.f, 0.f);
    const uint2* h2p = (const uint2*)hbf;
    int dcap = deg < 128 ? deg : 128;
#pragma unroll 2
    for (int j = 0; j < dcap; j++) {
        int src = s_src[w][j];
        float wgt = s_wf[w][j * 4 + hd] * inv;
        uint2 u = h2p[(size_t)src * 64 + l];
        accv.x += wgt * __uint_as_float(u.x << 16);
        accv.y += wgt * __uint_as_float(u.x & 0xffff0000u);
        accv.z += wgt * __uint_as_float(u.y << 16);
        accv.w += wgt * __uint_as_float(u.y & 0xffff0000u);
    }
    for (int j = 128; j < deg; j++) {             // rare
        int src = srcsort[base + j];
        float4 a = asrc4[src];
        float ah = hd == 0 ? a.x : hd == 1 ? a.y : hd == 2 ? a.z : a.w;
        float wgt = __expf(lrelu(ah + adh) - mh) * inv;
        uint2 u = h2p[(size_t)src * 64 + l];
        accv.x += wgt * __uint_as_float(u.x << 16);
        accv.y += wgt * __uint_as_float(u.x & 0xffff0000u);
        accv.z += wgt * __uint_as_float(u.y << 16);
        accv.w += wgt * __uint_as_float(u.y & 0xffff0000u);
    }
    out4[dst * 64 + l] = make_float4(accv.x + bgv.x, accv.y + bgv.y,
                                     accv.z + bgv.z, accv.w + bgv.w);
}

// ---------- 10. column stats of outpre (256 cols, float4) ----------
__global__ __launch_bounds__(256) void k_bn3_stats(
        const float* __restrict__ op, float* __restrict__ sum, float* __restrict__ sq) {
    __shared__ float4 ta[256];
    __shared__ float4 tb[256];
    int t = threadIdx.x;
    int cq = t & 63, rsub = t >> 6;
    int c4 = cq << 2;
    float4 a = make_float4(0.f, 0.f, 0.f, 0.f);
    float4 b = make_float4(0.f, 0.f, 0.f, 0.f);
    for (int r = blockIdx.x * 4 + rsub; r < N_; r += gridDim.x * 4) {
        float4 v = *(const float4*)(op + (size_t)r * 256 + c4);
        a.x += v.x; a.y += v.y; a.z += v.z; a.w += v.w;
        b.x += v.x * v.x; b.y += v.y * v.y; b.z += v.z * v.z; b.w += v.w * v.w;
    }
    ta[t] = a; tb[t] = b;
    __syncthreads();
    if (t < 64) {
        float4 sa = ta[t], sb = tb[t];
#pragma unroll
        for (int r = 1; r < 4; r++) {
            float4 xa = ta[r * 64 + t], xb = tb[r * 64 + t];
            sa.x += xa.x; sa.y += xa.y; sa.z += xa.z; sa.w += xa.w;
            sb.x += xb.x; sb.y += xb.y; sb.z += xb.z; sb.w += xb.w;
        }
        int c = t << 2;
        atomicAdd(&sum[c + 0], sa.x); atomicAdd(&sum[c + 1], sa.y);
        atomicAdd(&sum[c + 2], sa.z); atomicAdd(&sum[c + 3], sa.w);
        atomicAdd(&sq[c + 0], sb.x);  atomicAdd(&sq[c + 1], sb.y);
        atomicAdd(&sq[c + 2], sb.z);  atomicAdd(&sq[c + 3], sb.w);
    }
}

// ---------- 11. graph mean-pool of elu(bn3(outpre)) + final MLP, fused ----------
__global__ __launch_bounds__(256) void k_pool_mlp(
        const float* __restrict__ op, const int* __restrict__ batch,
        const float* __restrict__ bn3sum, const float* __restrict__ bn3sq,
        const float* __restrict__ bn3g, const float* __restrict__ bn3b,
        const float* __restrict__ W1, const float* __restrict__ b1,
        const float* __restrict__ W2, const float* __restrict__ b2,
        float* __restrict__ out) {
    __shared__ float4 tile[256];
    __shared__ float  pl[256];
    __shared__ float  hm[64];
    int g = blockIdx.x;                  // grid 512
    int t = threadIdx.x;
    int cq = t & 63, rsub = t >> 6;
    int c4 = cq << 2;
    int lo = 0, hi = N_;
    while (lo < hi) { int mid = (lo + hi) >> 1; if (batch[mid] < g) lo = mid + 1; else hi = mid; }
    int start = lo;
    hi = N_;
    while (lo < hi) { int mid = (lo + hi) >> 1; if (batch[mid] < g + 1) lo = mid + 1; else hi = mid; }
    int end = lo;
    float scv[4], shv[4];
#pragma unroll
    for (int k = 0; k < 4; k++) {
        int c = c4 + k;
        float mu  = bn3sum[c] / (float)N_;
        float var = bn3sq[c] / (float)N_ - mu * mu;
        float s   = bn3g[c] * rsqrtf(var + EPS_);
        scv[k] = s; shv[k] = bn3b[c] - mu * s;
    }
    float4 acc = make_float4(0.f, 0.f, 0.f, 0.f);
    for (int n = start + rsub; n < end; n += 4) {
        float4 v = *(const float4*)(op + (size_t)n * 256 + c4);
        float e0 = v.x * scv[0] + shv[0], e1 = v.y * scv[1] + shv[1];
        float e2 = v.z * scv[2] + shv[2], e3 = v.w * scv[3] + shv[3];
        acc.x += (e0 > 0.f) ? e0 : expm1f(e0);
        acc.y += (e1 > 0.f) ? e1 : expm1f(e1);
        acc.z += (e2 > 0.f) ? e2 : expm1f(e2);
        acc.w += (e3 > 0.f) ? e3 : expm1f(e3);
    }
    tile[t] = acc;
    __syncthreads();
    if (t < 64) {
        float4 s = tile[t];
#pragma unroll
        for (int r = 1; r < 4; r++) {
            float4 xv = tile[r * 64 + t];
            s.x += xv.x; s.y += xv.y; s.z += xv.z; s.w += xv.w;
        }
        float icn = 1.f / fmaxf((float)(end - start), 1.f);
        ((float4*)pl)[t] = make_float4(s.x * icn, s.y * icn, s.z * icn, s.w * icn);
    }
    __syncthreads();
    // hmlp = relu(pl @ W1.T + b1): 4 threads per output j
    {
        int j = t >> 2, part = t & 3;
        const float* w1r = W1 + j * 256 + part * 64;
        const float* plr = pl + part * 64;
        float a = 0.f;
#pragma unroll
        for (int c = 0; c < 64; c++) a += w1r[c] * plr[c];
        a += __shfl_xor(a, 1);
        a += __shfl_xor(a, 2);
        if (part == 0) hm[j] = fmaxf(a + b1[j], 0.f);
    }
    __syncthreads();
    if (t < 128) {
        int j = t >> 6, k = t & 63;
        float p = W2[j * 64 + k] * hm[k];
        for (int m = 1; m < 64; m <<= 1) p += __shfl_xor(p, m);
        if (k == 0) out[g * 2 + j] = p + b2[j];
    }
}

extern "C" void kernel_launch(void* const* d_in, const int* in_sizes, int n_in,
                              void* d_out, int out_size, void* d_ws, size_t ws_size,
                              hipStream_t stream) {
    const float* x    = (const float*)d_in[0];
    const int*   ei   = (const int*)d_in[1];
    const int*   batch= (const int*)d_in[2];
    const float* lng  = (const float*)d_in[3];
    const float* lnb  = (const float*)d_in[4];
    const float* bn1g = (const float*)d_in[5];
    const float* bn1b = (const float*)d_in[6];
    const float* Wc   = (const float*)d_in[7];
    const float* bc   = (const float*)d_in[8];
    const float* bn2g = (const float*)d_in[9];
    const float* bn2b = (const float*)d_in[10];
    const float* Wp   = (const float*)d_in[11];
    const float* bp   = (const float*)d_in[12];
    const float* Wg   = (const float*)d_in[13];
    const float* atts = (const float*)d_in[14];
    const float* attd = (const float*)d_in[15];
    const float* bg   = (const float*)d_in[16];
    const float* bn3g = (const float*)d_in[17];
    const float* bn3b = (const float*)d_in[18];
    const float* W1   = (const float*)d_in[19];
    const float* b1   = (const float*)d_in[20];
    const float* W2   = (const float*)d_in[21];
    const float* b2   = (const float*)d_in[22];
    float* out = (float*)d_out;

    char* w8 = (char*)d_ws;
    float* bn1sum = (float*)(w8 + OFF_BN1SUM);
    float* bn1sq  = (float*)(w8 + OFF_BN1SQ);
    float* bn2sum = (float*)(w8 + OFF_BN2SUM);
    float* bn2sq  = (float*)(w8 + OFF_BN2SQ);
    float* bn3sum = (float*)(w8 + OFF_BN3SUM);
    float* bn3sq  = (float*)(w8 + OFF_BN3SQ);
    int*   count  = (int*)(w8 + OFF_COUNT);
    int*   cur    = (int*)(w8 + OFF_CUR);
    int*   offs   = (int*)(w8 + OFF_OFFS);
    int*   part   = (int*)(w8 + OFF_PART);
    float* Wc2t   = (float*)(w8 + OFF_WC2);
    float* c2     = (float*)(w8 + OFF_C2);
    float* Wp2    = (float*)(w8 + OFF_WP2);
    float* cp     = (float*)(w8 + OFF_CP);
    float* Wgt    = (float*)(w8 + OFF_WGT);
    float* asrc   = (float*)(w8 + OFF_ASRC);
    float* adst   = (float*)(w8 + OFF_ADST);
    int*   srcs   = (int*)(w8 + OFF_SRCS);
    float* z      = (float*)(w8 + OFF_Z);
    ushort4* hbf  = (ushort4*)(w8 + OFF_H);
    float* outp   = (float*)(w8 + OFF_OUTP);

    hipMemsetAsync(d_ws, 0, ZERO_BYTES, stream);

    const int HISTB = (E_ + 511) / 512;
    k_bn1_hist<<<256 + HISTB, 512, 0, stream>>>(x, bn1sum, bn1sq, ei, count);
    k_fold1<<<1, 512, 0, stream>>>(bn1sum, bn1sq, bn1g, bn1b, Wc, bc, Wc2t, c2);
    k_z<<<(N_ + 63) / 64, 512, 0, stream>>>(x, Wc2t, c2, lng, lnb, z, bn2sum, bn2sq);
    const int SCANB = (N_ + 1023) / 1024;
    k_scan1<<<SCANB, 1024, 0, stream>>>(count, offs, part);
    k_scan23<<<SCANB, 1024, 0, stream>>>(offs, part);
    k_fold2_wgt<<<65, 256, 0, stream>>>(bn2sum, bn2sq, bn2g, bn2b, Wp, bp, Wp2, cp, Wg, Wgt);
    k_scatter<<<E_ / 256, 256, 0, stream>>>(ei, offs, cur, srcs);
    k_h2<<<(N_ + 127) / 128, 512, 0, stream>>>(z, Wp2, cp, Wgt, atts, attd, hbf, asrc, adst);
    k_agg<<<N_ / 4, 256, 0, stream>>>(count, offs, srcs, asrc, adst, hbf, bg, outp);
    k_bn3_stats<<<256, 256, 0, stream>>>(outp, bn3sum, bn3sq);
    k_pool_mlp<<<G_, 256, 0, stream>>>(outp, batch, bn3sum, bn3sq, bn3g, bn3b,
                                       W1, b1, W2, b2, out);
}